// Round 1
// baseline (481.818 us; speedup 1.0000x reference)
//
#include <hip/hip_runtime.h>
#include <hip/hip_bf16.h>

typedef float  f32x4  __attribute__((ext_vector_type(4)));
typedef float  fvec4  __attribute__((ext_vector_type(4)));
typedef __bf16 bf16x8 __attribute__((ext_vector_type(8)));
typedef unsigned short u16x8 __attribute__((ext_vector_type(8)));

#define DEVINL __device__ __forceinline__

constexpr int D_MODEL = 1024;
constexpr int NH      = 16;
constexpr int DK      = 64;
constexpr int SEQ     = 2048;
constexpr int BATCH   = 4;
constexpr int M_TOK   = BATCH * SEQ;   // 8192

DEVINL unsigned short f32_to_bf16_u(float f) {
    unsigned int u = __builtin_bit_cast(unsigned int, f);
    u = (u + 0x7FFFu + ((u >> 16) & 1u)) >> 16;
    return (unsigned short)u;
}

// ---------------------------------------------------------------------------
// NT GEMM: C[m,n] = sum_k A[m,k]*W[n,k] + bias[n]
// M=8192, N=1024, K=1024. A fp32 or bf16; W fp32 (converted in staging).
// Output: SPLIT_HEADS -> bf16 [B,H,S,DK]; else fp32 [M,N].
// 128x128 tile, BK=64, 4 waves each 64x64 (4x4 frags of 16x16x32 bf16 MFMA).
// LDS tiles XOR-swizzled (byte ^= (row&7)<<4) so frag reads are 2-way max.
// ---------------------------------------------------------------------------
template<bool A_BF16, bool SPLIT_HEADS>
__global__ __launch_bounds__(256) void gemm_nt(const void* __restrict__ Ap,
                                               const float* __restrict__ Wp,
                                               const float* __restrict__ bias,
                                               void* __restrict__ outp)
{
    constexpr int BM = 128, BN = 128, BK = 64;
    constexpr int K = D_MODEL, N = D_MODEL;
    __shared__ char lds[(BM * BK + BN * BK) * 2];
    char* As = lds;
    char* Bs = lds + BM * BK * 2;

    const int tid  = threadIdx.x;
    const int lane = tid & 63;
    const int wave = tid >> 6;
    const int wr = (wave >> 1) * 64;
    const int wc = (wave & 1) * 64;
    const int m0 = blockIdx.y * BM;
    const int n0 = blockIdx.x * BN;

    f32x4 acc[4][4] = {};

    for (int kt = 0; kt < K; kt += BK) {
        __syncthreads();
        // stage A and B tiles: each 128x64 bf16 = 1024 chunks of 16B; 4/thread
        #pragma unroll
        for (int i = 0; i < 4; ++i) {
            int chunk = tid + i * 256;
            int r   = chunk >> 3;
            int c16 = chunk & 7;
            int boff = (chunk * 16) ^ ((r & 7) << 4);
            if constexpr (A_BF16) {
                u16x8 v = *reinterpret_cast<const u16x8*>(
                    (const unsigned short*)Ap + (size_t)(m0 + r) * K + kt + c16 * 8);
                *reinterpret_cast<u16x8*>(As + boff) = v;
            } else {
                const float* src = (const float*)Ap + (size_t)(m0 + r) * K + kt + c16 * 8;
                fvec4 v0 = *reinterpret_cast<const fvec4*>(src);
                fvec4 v1 = *reinterpret_cast<const fvec4*>(src + 4);
                u16x8 o;
                #pragma unroll
                for (int j = 0; j < 4; ++j) { o[j] = f32_to_bf16_u(v0[j]); o[j + 4] = f32_to_bf16_u(v1[j]); }
                *reinterpret_cast<u16x8*>(As + boff) = o;
            }
            {
                const float* src = Wp + (size_t)(n0 + r) * K + kt + c16 * 8;
                fvec4 v0 = *reinterpret_cast<const fvec4*>(src);
                fvec4 v1 = *reinterpret_cast<const fvec4*>(src + 4);
                u16x8 o;
                #pragma unroll
                for (int j = 0; j < 4; ++j) { o[j] = f32_to_bf16_u(v0[j]); o[j + 4] = f32_to_bf16_u(v1[j]); }
                *reinterpret_cast<u16x8*>(Bs + boff) = o;
            }
        }
        __syncthreads();
        #pragma unroll
        for (int kk = 0; kk < 2; ++kk) {
            bf16x8 af[4], bfr[4];
            #pragma unroll
            for (int mi = 0; mi < 4; ++mi) {
                int r = wr + mi * 16 + (lane & 15);
                int boff = (r * 128 + kk * 64 + (lane >> 4) * 16) ^ ((r & 7) << 4);
                af[mi] = *reinterpret_cast<const bf16x8*>(As + boff);
            }
            #pragma unroll
            for (int ni = 0; ni < 4; ++ni) {
                int r = wc + ni * 16 + (lane & 15);
                int boff = (r * 128 + kk * 64 + (lane >> 4) * 16) ^ ((r & 7) << 4);
                bfr[ni] = *reinterpret_cast<const bf16x8*>(Bs + boff);
            }
            #pragma unroll
            for (int mi = 0; mi < 4; ++mi)
                #pragma unroll
                for (int ni = 0; ni < 4; ++ni)
                    acc[mi][ni] = __builtin_amdgcn_mfma_f32_16x16x32_bf16(
                        af[mi], bfr[ni], acc[mi][ni], 0, 0, 0);
        }
    }

    // epilogue: C/D layout col = lane&15, row = (lane>>4)*4 + reg
    const int rl = (lane >> 4) * 4;
    #pragma unroll
    for (int mi = 0; mi < 4; ++mi) {
        #pragma unroll
        for (int ni = 0; ni < 4; ++ni) {
            int col = n0 + wc + ni * 16 + (lane & 15);
            float bv = bias[col];
            #pragma unroll
            for (int r = 0; r < 4; ++r) {
                int row = m0 + wr + mi * 16 + rl + r;
                float v = acc[mi][ni][r] + bv;
                if constexpr (SPLIT_HEADS) {
                    int bb = row >> 11, s = row & (SEQ - 1);
                    int h = col >> 6, dk = col & (DK - 1);
                    ((unsigned short*)outp)[((((size_t)bb * NH + h) * SEQ) + s) * DK + dk]
                        = f32_to_bf16_u(v);
                } else {
                    ((float*)outp)[(size_t)row * N + col] = v;
                }
            }
        }
    }
}

// ---------------------------------------------------------------------------
// Flash attention: grid (S/64, B*H), 256 thr = 4 waves, each wave 16 q-rows.
// K tile XOR-swizzled in LDS; V staged transposed [d][t]; P via per-wave LDS.
// ---------------------------------------------------------------------------
__global__ __launch_bounds__(256) void attn_kernel(const unsigned short* __restrict__ qb,
                                                   const unsigned short* __restrict__ kb,
                                                   const unsigned short* __restrict__ vb,
                                                   unsigned short* __restrict__ ob)
{
    constexpr int KBLK = 64;
    __shared__ char Klds[KBLK * DK * 2];                  // 8 KB, swizzled
    __shared__ unsigned short Vt[DK][KBLK + 8];           // transposed V, padded
    __shared__ unsigned short Plds[4][16][KBLK + 8];      // per-wave P, padded

    const int tid  = threadIdx.x;
    const int lane = tid & 63;
    const int wave = tid >> 6;
    const int bh   = blockIdx.y;
    const int q0   = blockIdx.x * 64;
    const size_t base = (size_t)bh * SEQ * DK;

    // Q fragments (A-frag: row = lane&15, k = kk*32 + (lane>>4)*8 + j)
    bf16x8 qf[2];
    {
        int qrow = q0 + wave * 16 + (lane & 15);
        const unsigned short* qp = qb + base + (size_t)qrow * DK + (lane >> 4) * 8;
        qf[0] = *reinterpret_cast<const bf16x8*>(qp);
        qf[1] = *reinterpret_cast<const bf16x8*>(qp + 32);
    }

    float m_run[4], l_run[4];
    f32x4 oacc[4] = {};
    #pragma unroll
    for (int r = 0; r < 4; ++r) { m_run[r] = -1e30f; l_run[r] = 0.f; }

    for (int t0 = 0; t0 < SEQ; t0 += KBLK) {
        __syncthreads();
        // stage K: 64x64 bf16 = 512 chunks of 16B, swizzled
        #pragma unroll
        for (int i = 0; i < 2; ++i) {
            int chunk = tid + i * 256;
            int r = chunk >> 3, c16 = chunk & 7;
            int boff = (chunk * 16) ^ ((r & 7) << 4);
            u16x8 v = *reinterpret_cast<const u16x8*>(kb + base + (size_t)(t0 + r) * DK + c16 * 8);
            *reinterpret_cast<u16x8*>(Klds + boff) = v;
        }
        // stage V transposed
        #pragma unroll
        for (int i = 0; i < 2; ++i) {
            int t  = (tid >> 3) + i * 32;
            int d0 = (tid & 7) * 8;
            u16x8 v = *reinterpret_cast<const u16x8*>(vb + base + (size_t)(t0 + t) * DK + d0);
            #pragma unroll
            for (int j = 0; j < 8; ++j) Vt[d0 + j][t] = v[j];
        }
        __syncthreads();

        // scores: 4 col-frags; B-frag = K rows (NT)
        f32x4 sc[4];
        #pragma unroll
        for (int nb = 0; nb < 4; ++nb) {
            f32x4 a = {};
            #pragma unroll
            for (int kk = 0; kk < 2; ++kk) {
                int r = nb * 16 + (lane & 15);
                int boff = (r * 128 + kk * 64 + (lane >> 4) * 16) ^ ((r & 7) << 4);
                bf16x8 kf = *reinterpret_cast<const bf16x8*>(Klds + boff);
                a = __builtin_amdgcn_mfma_f32_16x16x32_bf16(qf[kk], kf, a, 0, 0, 0);
            }
            sc[nb] = a * 0.125f;   // 1/sqrt(64)
        }

        // online softmax per q-row (4 rows per lane; 16-lane butterfly)
        #pragma unroll
        for (int r = 0; r < 4; ++r) {
            float mx = fmaxf(fmaxf(sc[0][r], sc[1][r]), fmaxf(sc[2][r], sc[3][r]));
            #pragma unroll
            for (int off = 1; off < 16; off <<= 1) mx = fmaxf(mx, __shfl_xor(mx, off));
            float m_new = fmaxf(m_run[r], mx);
            float alpha = __expf(m_run[r] - m_new);
            float rsum = 0.f;
            #pragma unroll
            for (int nb = 0; nb < 4; ++nb) {
                float p = __expf(sc[nb][r] - m_new);
                sc[nb][r] = p;
                rsum += p;
            }
            #pragma unroll
            for (int off = 1; off < 16; off <<= 1) rsum += __shfl_xor(rsum, off);
            l_run[r] = l_run[r] * alpha + rsum;
            m_run[r] = m_new;
            #pragma unroll
            for (int db = 0; db < 4; ++db) oacc[db][r] *= alpha;
        }

        // P -> LDS (per-wave, no barrier needed)
        #pragma unroll
        for (int nb = 0; nb < 4; ++nb) {
            int t = nb * 16 + (lane & 15);
            #pragma unroll
            for (int r = 0; r < 4; ++r) {
                int m = (lane >> 4) * 4 + r;
                Plds[wave][m][t] = f32_to_bf16_u(sc[nb][r]);
            }
        }

        // PV: A-frag from Plds, B-frag from Vt (contiguous in t)
        #pragma unroll
        for (int kk = 0; kk < 2; ++kk) {
            bf16x8 pf = *reinterpret_cast<const bf16x8*>(
                &Plds[wave][lane & 15][kk * 32 + (lane >> 4) * 8]);
            #pragma unroll
            for (int db = 0; db < 4; ++db) {
                bf16x8 vf = *reinterpret_cast<const bf16x8*>(
                    &Vt[db * 16 + (lane & 15)][kk * 32 + (lane >> 4) * 8]);
                oacc[db] = __builtin_amdgcn_mfma_f32_16x16x32_bf16(pf, vf, oacc[db], 0, 0, 0);
            }
        }
    }

    // epilogue: write combined [B*S, D_MODEL] bf16
    const int bb = bh >> 4, h = bh & 15;
    #pragma unroll
    for (int db = 0; db < 4; ++db) {
        int col = h * DK + db * 16 + (lane & 15);
        #pragma unroll
        for (int r = 0; r < 4; ++r) {
            int srow = q0 + wave * 16 + (lane >> 4) * 4 + r;
            float v = oacc[db][r] / l_run[r];
            ob[((size_t)(bb * SEQ) + srow) * D_MODEL + col] = f32_to_bf16_u(v);
        }
    }
}

extern "C" void kernel_launch(void* const* d_in, const int* in_sizes, int n_in,
                              void* d_out, int out_size, void* d_ws, size_t ws_size,
                              hipStream_t stream)
{
    const float* Q  = (const float*)d_in[0];
    const float* K_ = (const float*)d_in[1];
    const float* V  = (const float*)d_in[2];
    const float* Wq = (const float*)d_in[3];
    const float* bq = (const float*)d_in[4];
    const float* Wk = (const float*)d_in[5];
    const float* bk = (const float*)d_in[6];
    const float* Wv = (const float*)d_in[7];
    const float* bv = (const float*)d_in[8];
    const float* Wo = (const float*)d_in[9];
    const float* bo = (const float*)d_in[10];
    float* out = (float*)d_out;

    const size_t SZ = (size_t)M_TOK * D_MODEL;  // elements
    unsigned short* qh = (unsigned short*)d_ws;  // [B,H,S,DK] bf16
    unsigned short* kh = qh + SZ;
    unsigned short* vh = kh + SZ;
    unsigned short* ah = vh + SZ;                // [B*S, D_MODEL] bf16

    dim3 gg(D_MODEL / 128, M_TOK / 128);
    gemm_nt<false, true><<<gg, 256, 0, stream>>>(Q,  Wq, bq, qh);
    gemm_nt<false, true><<<gg, 256, 0, stream>>>(K_, Wk, bk, kh);
    gemm_nt<false, true><<<gg, 256, 0, stream>>>(V,  Wv, bv, vh);
    attn_kernel<<<dim3(SEQ / 64, BATCH * NH), 256, 0, stream>>>(qh, kh, vh, ah);
    gemm_nt<true, false><<<gg, 256, 0, stream>>>(ah, Wo, bo, out);
}

// Round 2
// 481.502 us; speedup vs baseline: 1.0007x; 1.0007x over previous
//
#include <hip/hip_runtime.h>
#include <hip/hip_bf16.h>

typedef float  f32x4  __attribute__((ext_vector_type(4)));
typedef float  fvec4  __attribute__((ext_vector_type(4)));
typedef __bf16 bf16x8 __attribute__((ext_vector_type(8)));
typedef unsigned short u16x8 __attribute__((ext_vector_type(8)));

#define DEVINL __device__ __forceinline__

constexpr int D_MODEL = 1024;
constexpr int NH      = 16;
constexpr int DK      = 64;
constexpr int SEQ     = 2048;
constexpr int BATCH   = 4;
constexpr int M_TOK   = BATCH * SEQ;   // 8192

DEVINL unsigned short f32_to_bf16_u(float f) {
    unsigned int u = __builtin_bit_cast(unsigned int, f);
    u = (u + 0x7FFFu + ((u >> 16) & 1u)) >> 16;
    return (unsigned short)u;
}

DEVINL float exp2_fast(float x) { return __builtin_amdgcn_exp2f(x); }

// ---------------------------------------------------------------------------
// NT GEMM: C[m,n] = (sum_k A[m,k]*W[n,k] + bias[n]) * out_scale
// M=8192, N=1024, K=1024. A fp32 or bf16; W fp32 (converted in staging).
// Output: SPLIT_HEADS -> bf16 [B,H,S,DK]; else fp32 [M,N].
// 128x128 tile, BK=64, 4 waves each 64x64 (4x4 frags of 16x16x32 bf16 MFMA).
// LDS tiles XOR-swizzled (byte ^= (row&7)<<4).
// ---------------------------------------------------------------------------
template<bool A_BF16, bool SPLIT_HEADS>
__global__ __launch_bounds__(256) void gemm_nt(const void* __restrict__ Ap,
                                               const float* __restrict__ Wp,
                                               const float* __restrict__ bias,
                                               void* __restrict__ outp,
                                               float out_scale)
{
    constexpr int BM = 128, BN = 128, BK = 64;
    constexpr int K = D_MODEL, N = D_MODEL;
    __shared__ char lds[(BM * BK + BN * BK) * 2];
    char* As = lds;
    char* Bs = lds + BM * BK * 2;

    const int tid  = threadIdx.x;
    const int lane = tid & 63;
    const int wave = tid >> 6;
    const int wr = (wave >> 1) * 64;
    const int wc = (wave & 1) * 64;
    const int m0 = blockIdx.y * BM;
    const int n0 = blockIdx.x * BN;

    f32x4 acc[4][4] = {};

    for (int kt = 0; kt < K; kt += BK) {
        __syncthreads();
        #pragma unroll
        for (int i = 0; i < 4; ++i) {
            int chunk = tid + i * 256;
            int r   = chunk >> 3;
            int c16 = chunk & 7;
            int boff = (chunk * 16) ^ ((r & 7) << 4);
            if constexpr (A_BF16) {
                u16x8 v = *reinterpret_cast<const u16x8*>(
                    (const unsigned short*)Ap + (size_t)(m0 + r) * K + kt + c16 * 8);
                *reinterpret_cast<u16x8*>(As + boff) = v;
            } else {
                const float* src = (const float*)Ap + (size_t)(m0 + r) * K + kt + c16 * 8;
                fvec4 v0 = *reinterpret_cast<const fvec4*>(src);
                fvec4 v1 = *reinterpret_cast<const fvec4*>(src + 4);
                u16x8 o;
                #pragma unroll
                for (int j = 0; j < 4; ++j) { o[j] = f32_to_bf16_u(v0[j]); o[j + 4] = f32_to_bf16_u(v1[j]); }
                *reinterpret_cast<u16x8*>(As + boff) = o;
            }
            {
                const float* src = Wp + (size_t)(n0 + r) * K + kt + c16 * 8;
                fvec4 v0 = *reinterpret_cast<const fvec4*>(src);
                fvec4 v1 = *reinterpret_cast<const fvec4*>(src + 4);
                u16x8 o;
                #pragma unroll
                for (int j = 0; j < 4; ++j) { o[j] = f32_to_bf16_u(v0[j]); o[j + 4] = f32_to_bf16_u(v1[j]); }
                *reinterpret_cast<u16x8*>(Bs + boff) = o;
            }
        }
        __syncthreads();
        #pragma unroll
        for (int kk = 0; kk < 2; ++kk) {
            bf16x8 af[4], bfr[4];
            #pragma unroll
            for (int mi = 0; mi < 4; ++mi) {
                int r = wr + mi * 16 + (lane & 15);
                int boff = (r * 128 + kk * 64 + (lane >> 4) * 16) ^ ((r & 7) << 4);
                af[mi] = *reinterpret_cast<const bf16x8*>(As + boff);
            }
            #pragma unroll
            for (int ni = 0; ni < 4; ++ni) {
                int r = wc + ni * 16 + (lane & 15);
                int boff = (r * 128 + kk * 64 + (lane >> 4) * 16) ^ ((r & 7) << 4);
                bfr[ni] = *reinterpret_cast<const bf16x8*>(Bs + boff);
            }
            #pragma unroll
            for (int mi = 0; mi < 4; ++mi)
                #pragma unroll
                for (int ni = 0; ni < 4; ++ni)
                    acc[mi][ni] = __builtin_amdgcn_mfma_f32_16x16x32_bf16(
                        af[mi], bfr[ni], acc[mi][ni], 0, 0, 0);
        }
    }

    const int rl = (lane >> 4) * 4;
    #pragma unroll
    for (int mi = 0; mi < 4; ++mi) {
        #pragma unroll
        for (int ni = 0; ni < 4; ++ni) {
            int col = n0 + wc + ni * 16 + (lane & 15);
            float bv = bias[col];
            #pragma unroll
            for (int r = 0; r < 4; ++r) {
                int row = m0 + wr + mi * 16 + rl + r;
                float v = (acc[mi][ni][r] + bv) * out_scale;
                if constexpr (SPLIT_HEADS) {
                    int bb = row >> 11, s = row & (SEQ - 1);
                    int h = col >> 6, dk = col & (DK - 1);
                    ((unsigned short*)outp)[((((size_t)bb * NH + h) * SEQ) + s) * DK + dk]
                        = f32_to_bf16_u(v);
                } else {
                    ((float*)outp)[(size_t)row * N + col] = v;
                }
            }
        }
    }
}

// ---------------------------------------------------------------------------
// Flash attention: grid (S/128, B*H), 256 thr = 4 waves, each wave 32 q-rows.
// Scores arrive pre-scaled by 0.125*log2(e) (folded into the Q projection),
// so softmax runs in exp2 domain with raw v_exp_f32.
// LDS: K 64x64 swizzled (8K); Vt[d][t] 160B rows + XOR((d>>3)&7)<<4 (10K);
//      per-wave P[32][64] 160B rows + XOR((row&7)<<4 (20K). Total ~39K.
// ---------------------------------------------------------------------------
__global__ __launch_bounds__(256) void attn_kernel(const unsigned short* __restrict__ qb,
                                                   const unsigned short* __restrict__ kb,
                                                   const unsigned short* __restrict__ vb,
                                                   unsigned short* __restrict__ ob)
{
    constexpr int KBLK = 64;
    constexpr int QW   = 32;          // q-rows per wave
    constexpr float THR = 11.0f;      // defer-max threshold (log2 units, P <= 2^11)
    __shared__ char Klds[KBLK * DK * 2];   // 8 KB
    __shared__ char VtB[DK * 160];         // 10 KB
    __shared__ char PB[4][QW * 160];       // 20 KB

    const int tid  = threadIdx.x;
    const int lane = tid & 63;
    const int l15  = lane & 15;
    const int hi   = lane >> 4;
    const int wave = tid >> 6;
    const int bh   = blockIdx.y;
    const int q0   = blockIdx.x * 128;
    const size_t base = (size_t)bh * SEQ * DK;

    // Q fragments: A-frag row = l15, k = kk*32 + hi*8 + j
    bf16x8 qf[2][2];
    #pragma unroll
    for (int mq = 0; mq < 2; ++mq) {
        int qrow = q0 + wave * QW + mq * 16 + l15;
        const unsigned short* qp = qb + base + (size_t)qrow * DK + hi * 8;
        qf[mq][0] = *reinterpret_cast<const bf16x8*>(qp);
        qf[mq][1] = *reinterpret_cast<const bf16x8*>(qp + 32);
    }

    float m_run[2][4], l_run[2][4];
    f32x4 oacc[2][4] = {};
    #pragma unroll
    for (int mq = 0; mq < 2; ++mq)
        #pragma unroll
        for (int r = 0; r < 4; ++r) { m_run[mq][r] = -1e30f; l_run[mq][r] = 0.f; }

    for (int t0 = 0; t0 < SEQ; t0 += KBLK) {
        __syncthreads();
        // stage K: 64x64 bf16, b128 chunks, XOR swizzle
        #pragma unroll
        for (int i = 0; i < 2; ++i) {
            int chunk = tid + i * 256;
            int r = chunk >> 3, c16 = chunk & 7;
            int boff = (chunk * 16) ^ ((r & 7) << 4);
            u16x8 v = *reinterpret_cast<const u16x8*>(kb + base + (size_t)(t0 + r) * DK + c16 * 8);
            *reinterpret_cast<u16x8*>(Klds + boff) = v;
        }
        // stage V transposed: element (d,t) at byte (d*160 + 2t) ^ ((d>>3)&7)<<4
        // write conflicts: bank = (8j + t/2) ^ 4*(tid&7) -> 2-way (free)
        #pragma unroll
        for (int i = 0; i < 2; ++i) {
            int t  = (tid >> 3) + i * 32;
            int d0 = (tid & 7) * 8;
            u16x8 v = *reinterpret_cast<const u16x8*>(vb + base + (size_t)(t0 + t) * DK + d0);
            #pragma unroll
            for (int j = 0; j < 8; ++j) {
                int d = d0 + j;
                int boff = (d * 160 + t * 2) ^ (((d >> 3) & 7) << 4);
                *reinterpret_cast<unsigned short*>(VtB + boff) = v[j];
            }
        }
        __syncthreads();

        // QK^T: kf shared across both m-frags
        f32x4 sc[2][4] = {};
        #pragma unroll
        for (int kk = 0; kk < 2; ++kk) {
            #pragma unroll
            for (int nb = 0; nb < 4; ++nb) {
                int r = nb * 16 + l15;
                int boff = (r * 128 + kk * 64 + hi * 16) ^ ((r & 7) << 4);
                bf16x8 kfr = *reinterpret_cast<const bf16x8*>(Klds + boff);
                sc[0][nb] = __builtin_amdgcn_mfma_f32_16x16x32_bf16(qf[0][kk], kfr, sc[0][nb], 0, 0, 0);
                sc[1][nb] = __builtin_amdgcn_mfma_f32_16x16x32_bf16(qf[1][kk], kfr, sc[1][nb], 0, 0, 0);
            }
        }

        // ---- online softmax (log2 domain), defer-max rescale ----
        float mx[2][4];
        int need = 0;
        #pragma unroll
        for (int mq = 0; mq < 2; ++mq)
            #pragma unroll
            for (int r = 0; r < 4; ++r) {
                float m = fmaxf(fmaxf(sc[mq][0][r], sc[mq][1][r]),
                                fmaxf(sc[mq][2][r], sc[mq][3][r]));
                #pragma unroll
                for (int off = 1; off < 16; off <<= 1) m = fmaxf(m, __shfl_xor(m, off));
                mx[mq][r] = m;
                need |= (m > m_run[mq][r] + THR) ? 1 : 0;
            }
        if (__any(need)) {
            #pragma unroll
            for (int mq = 0; mq < 2; ++mq)
                #pragma unroll
                for (int r = 0; r < 4; ++r) {
                    float mn = fmaxf(m_run[mq][r], mx[mq][r]);
                    float al = exp2_fast(m_run[mq][r] - mn);
                    m_run[mq][r] = mn;
                    l_run[mq][r] *= al;
                    #pragma unroll
                    for (int db = 0; db < 4; ++db) oacc[mq][db][r] *= al;
                }
        }

        // P = exp2(sc - m), write bf16 to per-wave LDS, accumulate row sums
        #pragma unroll
        for (int mq = 0; mq < 2; ++mq) {
            float rs[4] = {0.f, 0.f, 0.f, 0.f};
            #pragma unroll
            for (int nb = 0; nb < 4; ++nb)
                #pragma unroll
                for (int r = 0; r < 4; ++r) {
                    float p = exp2_fast(sc[mq][nb][r] - m_run[mq][r]);
                    rs[r] += p;
                    int row = mq * 16 + hi * 4 + r;
                    int boff = (row * 160 + (nb * 16 + l15) * 2) ^ ((row & 7) << 4);
                    *reinterpret_cast<unsigned short*>(PB[wave] + boff) = f32_to_bf16_u(p);
                }
            #pragma unroll
            for (int r = 0; r < 4; ++r) {
                float s = rs[r];
                #pragma unroll
                for (int off = 1; off < 16; off <<= 1) s += __shfl_xor(s, off);
                l_run[mq][r] += s;
            }
        }

        // PV: pf from PB, vf from VtB (both swizzled b128 reads)
        #pragma unroll
        for (int kk = 0; kk < 2; ++kk) {
            bf16x8 pfr[2];
            #pragma unroll
            for (int mq = 0; mq < 2; ++mq) {
                int row = mq * 16 + l15;
                int boff = (row * 160 + (kk * 32 + hi * 8) * 2) ^ ((row & 7) << 4);
                pfr[mq] = *reinterpret_cast<const bf16x8*>(PB[wave] + boff);
            }
            #pragma unroll
            for (int db = 0; db < 4; ++db) {
                int d = db * 16 + l15;
                int boff = (d * 160 + (kk * 32 + hi * 8) * 2) ^ (((d >> 3) & 7) << 4);
                bf16x8 vfr = *reinterpret_cast<const bf16x8*>(VtB + boff);
                oacc[0][db] = __builtin_amdgcn_mfma_f32_16x16x32_bf16(pfr[0], vfr, oacc[0][db], 0, 0, 0);
                oacc[1][db] = __builtin_amdgcn_mfma_f32_16x16x32_bf16(pfr[1], vfr, oacc[1][db], 0, 0, 0);
            }
        }
    }

    // epilogue: write combined [B*S, D_MODEL] bf16
    const int bb = bh >> 4, h = bh & 15;
    #pragma unroll
    for (int mq = 0; mq < 2; ++mq)
        #pragma unroll
        for (int db = 0; db < 4; ++db) {
            int col = h * DK + db * 16 + l15;
            #pragma unroll
            for (int r = 0; r < 4; ++r) {
                int srow = q0 + wave * QW + mq * 16 + hi * 4 + r;
                float v = oacc[mq][db][r] / l_run[mq][r];
                ob[((size_t)(bb * SEQ) + srow) * D_MODEL + col] = f32_to_bf16_u(v);
            }
        }
}

extern "C" void kernel_launch(void* const* d_in, const int* in_sizes, int n_in,
                              void* d_out, int out_size, void* d_ws, size_t ws_size,
                              hipStream_t stream)
{
    const float* Q  = (const float*)d_in[0];
    const float* K_ = (const float*)d_in[1];
    const float* V  = (const float*)d_in[2];
    const float* Wq = (const float*)d_in[3];
    const float* bq = (const float*)d_in[4];
    const float* Wk = (const float*)d_in[5];
    const float* bk = (const float*)d_in[6];
    const float* Wv = (const float*)d_in[7];
    const float* bv = (const float*)d_in[8];
    const float* Wo = (const float*)d_in[9];
    const float* bo = (const float*)d_in[10];
    float* out = (float*)d_out;

    const size_t SZ = (size_t)M_TOK * D_MODEL;  // elements
    unsigned short* qh = (unsigned short*)d_ws;  // [B,H,S,DK] bf16
    unsigned short* kh = qh + SZ;
    unsigned short* vh = kh + SZ;
    unsigned short* ah = vh + SZ;                // [B*S, D_MODEL] bf16

    // Q projection pre-scaled by (1/sqrt(DK)) * log2(e) -> softmax in exp2 domain
    const float qscale = 0.125f * 1.4426950408889634f;

    dim3 gg(D_MODEL / 128, M_TOK / 128);
    gemm_nt<false, true><<<gg, 256, 0, stream>>>(Q,  Wq, bq, qh, qscale);
    gemm_nt<false, true><<<gg, 256, 0, stream>>>(K_, Wk, bk, kh, 1.0f);
    gemm_nt<false, true><<<gg, 256, 0, stream>>>(V,  Wv, bv, vh, 1.0f);
    attn_kernel<<<dim3(SEQ / 128, BATCH * NH), 256, 0, stream>>>(qh, kh, vh, ah);
    gemm_nt<true, false><<<gg, 256, 0, stream>>>(ah, Wo, bo, out, 1.0f);
}

// Round 6
// 267.579 us; speedup vs baseline: 1.8007x; 1.7995x over previous
//
#include <hip/hip_runtime.h>
#include <hip/hip_bf16.h>

typedef float  f32x4  __attribute__((ext_vector_type(4)));
typedef float  f32x16 __attribute__((ext_vector_type(16)));
typedef float  fvec4  __attribute__((ext_vector_type(4)));
typedef __bf16 bf16x8 __attribute__((ext_vector_type(8)));
typedef unsigned short u16x8 __attribute__((ext_vector_type(8)));
typedef unsigned int   u32x4 __attribute__((ext_vector_type(4)));

#define DEVINL __device__ __forceinline__

constexpr int D_MODEL = 1024;
constexpr int NH      = 16;
constexpr int DK      = 64;
constexpr int SEQ     = 2048;
constexpr int BATCH   = 4;
constexpr int M_TOK   = BATCH * SEQ;   // 8192

DEVINL unsigned short f32_to_bf16_u(float f) {
    unsigned int u = __builtin_bit_cast(unsigned int, f);
    u = (u + 0x7FFFu + ((u >> 16) & 1u)) >> 16;
    return (unsigned short)u;
}

DEVINL float exp2_fast(float x) { return __builtin_amdgcn_exp2f(x); }

DEVINL unsigned cvt_pk_bf16(float lo, float hi_) {
    unsigned d;
    asm("v_cvt_pk_bf16_f32 %0, %1, %2" : "=v"(d) : "v"(lo), "v"(hi_));
    return d;
}

// ---------------------------------------------------------------------------
// NT GEMM (unchanged): C[m,n] = (sum_k A[m,k]*W[n,k] + bias[n]) * s
// ---------------------------------------------------------------------------
template<bool A_BF16, bool SPLIT_HEADS>
__global__ __launch_bounds__(256) void gemm_nt(const void* __restrict__ Ap,
                                               const float* __restrict__ Wp,
                                               const float* __restrict__ bias,
                                               void* __restrict__ outp,
                                               float out_scale)
{
    constexpr int BM = 128, BN = 128, BK = 64;
    constexpr int K = D_MODEL, N = D_MODEL;
    __shared__ char lds[(BM * BK + BN * BK) * 2];
    char* As = lds;
    char* Bs = lds + BM * BK * 2;

    const int tid  = threadIdx.x;
    const int lane = tid & 63;
    const int wave = tid >> 6;
    const int wr = (wave >> 1) * 64;
    const int wc = (wave & 1) * 64;
    const int m0 = blockIdx.y * BM;
    const int n0 = blockIdx.x * BN;

    f32x4 acc[4][4] = {};

    for (int kt = 0; kt < K; kt += BK) {
        __syncthreads();
        #pragma unroll
        for (int i = 0; i < 4; ++i) {
            int chunk = tid + i * 256;
            int r   = chunk >> 3;
            int c16 = chunk & 7;
            int boff = (chunk * 16) ^ ((r & 7) << 4);
            if constexpr (A_BF16) {
                u16x8 v = *reinterpret_cast<const u16x8*>(
                    (const unsigned short*)Ap + (size_t)(m0 + r) * K + kt + c16 * 8);
                *reinterpret_cast<u16x8*>(As + boff) = v;
            } else {
                const float* src = (const float*)Ap + (size_t)(m0 + r) * K + kt + c16 * 8;
                fvec4 v0 = *reinterpret_cast<const fvec4*>(src);
                fvec4 v1 = *reinterpret_cast<const fvec4*>(src + 4);
                u16x8 o;
                #pragma unroll
                for (int j = 0; j < 4; ++j) { o[j] = f32_to_bf16_u(v0[j]); o[j + 4] = f32_to_bf16_u(v1[j]); }
                *reinterpret_cast<u16x8*>(As + boff) = o;
            }
            {
                const float* src = Wp + (size_t)(n0 + r) * K + kt + c16 * 8;
                fvec4 v0 = *reinterpret_cast<const fvec4*>(src);
                fvec4 v1 = *reinterpret_cast<const fvec4*>(src + 4);
                u16x8 o;
                #pragma unroll
                for (int j = 0; j < 4; ++j) { o[j] = f32_to_bf16_u(v0[j]); o[j + 4] = f32_to_bf16_u(v1[j]); }
                *reinterpret_cast<u16x8*>(Bs + boff) = o;
            }
        }
        __syncthreads();
        #pragma unroll
        for (int kk = 0; kk < 2; ++kk) {
            bf16x8 af[4], bfr[4];
            #pragma unroll
            for (int mi = 0; mi < 4; ++mi) {
                int r = wr + mi * 16 + (lane & 15);
                int boff = (r * 128 + kk * 64 + (lane >> 4) * 16) ^ ((r & 7) << 4);
                af[mi] = *reinterpret_cast<const bf16x8*>(As + boff);
            }
            #pragma unroll
            for (int ni = 0; ni < 4; ++ni) {
                int r = wc + ni * 16 + (lane & 15);
                int boff = (r * 128 + kk * 64 + (lane >> 4) * 16) ^ ((r & 7) << 4);
                bfr[ni] = *reinterpret_cast<const bf16x8*>(Bs + boff);
            }
            #pragma unroll
            for (int mi = 0; mi < 4; ++mi)
                #pragma unroll
                for (int ni = 0; ni < 4; ++ni)
                    acc[mi][ni] = __builtin_amdgcn_mfma_f32_16x16x32_bf16(
                        af[mi], bfr[ni], acc[mi][ni], 0, 0, 0);
        }
    }

    const int rl = (lane >> 4) * 4;
    #pragma unroll
    for (int mi = 0; mi < 4; ++mi) {
        #pragma unroll
        for (int ni = 0; ni < 4; ++ni) {
            int col = n0 + wc + ni * 16 + (lane & 15);
            float bv = bias[col];
            #pragma unroll
            for (int r = 0; r < 4; ++r) {
                int row = m0 + wr + mi * 16 + rl + r;
                float v = (acc[mi][ni][r] + bv) * out_scale;
                if constexpr (SPLIT_HEADS) {
                    int bb = row >> 11, s = row & (SEQ - 1);
                    int h = col >> 6, dk = col & (DK - 1);
                    ((unsigned short*)outp)[((((size_t)bb * NH + h) * SEQ) + s) * DK + dk]
                        = f32_to_bf16_u(v);
                } else {
                    ((float*)outp)[(size_t)row * N + col] = v;
                }
            }
        }
    }
}

// ---------------------------------------------------------------------------
// Flash attention, swapped-QK^T in-register softmax (m214-style).
// grid (SEQ/512, B*H), 512 thr = 8 waves, each wave 64 q-rows (2 x 32).
// 32x32x16 MFMA. S^T = mfma(K_frag, Q_frag): lane's col = its q-row ->
// softmax is lane-local (31 fmax) + one __shfl_xor(32) cross-half combine.
// ALL lane exchanges use __shfl_xor (defined semantics) -- permlane asm
// removed after R3-R5 elimination showed its direction/write-back behavior
// is under-determined from available docs.
// K/V staged in LDS in frag-contiguous chunk order -> all ds_read_b128
// wave-linear, zero bank conflicts. V transposed at gather time.
// Double-buffered LDS, loads issued early (T14), 1 barrier/tile.
// Defer-max rescale THR=11 (log2 domain, T13); scores pre-scaled by
// 0.125*log2(e) folded into the Q projection.
// ---------------------------------------------------------------------------
__global__ __launch_bounds__(512, 2) void attn_kernel(const unsigned short* __restrict__ qb,
                                                      const unsigned short* __restrict__ kb,
                                                      const unsigned short* __restrict__ vb,
                                                      unsigned short* __restrict__ ob)
{
    constexpr float THR = 11.0f;
    __shared__ char lds[32768];   // [2 bufs][K 8KB | V 8KB]

    const int tid  = threadIdx.x;
    const int lane = tid & 63;
    const int tl31 = lane & 31;
    const int hi   = lane >> 5;
    const int wave = tid >> 6;
    const int bh   = blockIdx.y;
    const int q0   = blockIdx.x * 512;
    const size_t base = (size_t)bh * SEQ * DK;

    // --- staging decode (thread-constant), frag-contiguous chunk = tid ---
    const int k_kt = tid >> 8, k_kd = (tid >> 6) & 3, k_hi = (tid >> 5) & 1, k_tl = tid & 31;
    const size_t k_goff = base + (size_t)(k_kt * 32 + k_tl) * DK + k_kd * 16 + k_hi * 8;
    const int v_tg = tid >> 6, v_dh = (tid >> 5) & 1, v_dl = tid & 31;
    const size_t v_goff = base + (size_t)(v_tg * 8) * DK + v_dh * 32 + v_dl;

    // --- Q fragments: B-operand, col=lane&31=q, k = kd*16 + hi*8 + j ---
    bf16x8 qf[2][4];
    #pragma unroll
    for (int qh = 0; qh < 2; ++qh)
        #pragma unroll
        for (int kd = 0; kd < 4; ++kd)
            qf[qh][kd] = *reinterpret_cast<const bf16x8*>(
                qb + base + (size_t)(q0 + wave * 64 + qh * 32 + tl31) * DK + kd * 16 + hi * 8);

    f32x16 oaccT[2][2] = {};            // [qh][dh], col=q, row=crow(r,hi)=d
    float m_run[2] = {-1e30f, -1e30f};
    float l_run[2] = {0.f, 0.f};

    // --- prologue: stage tile 0 into buf 0 ---
    {
        u16x8 kreg = *reinterpret_cast<const u16x8*>(kb + k_goff);
        unsigned short vg[8];
        #pragma unroll
        for (int j = 0; j < 8; ++j) vg[j] = vb[v_goff + (size_t)j * DK];
        *reinterpret_cast<u16x8*>(lds + tid * 16) = kreg;
        u16x8 vv;
        #pragma unroll
        for (int j = 0; j < 8; ++j) vv[j] = vg[j];
        *reinterpret_cast<u16x8*>(lds + 8192 + tid * 16) = vv;
    }
    __syncthreads();

    for (int t = 0; t < 32; ++t) {
        const int cur = t & 1;
        const char* Kr = lds + cur * 16384;
        const char* Vr = Kr + 8192;

        // issue next-tile global loads early (latency hides under compute)
        u16x8 knext;
        unsigned short vg[8];
        if (t < 31) {
            const int t0n = (t + 1) * 64;
            knext = *reinterpret_cast<const u16x8*>(kb + k_goff + (size_t)t0n * DK);
            #pragma unroll
            for (int j = 0; j < 8; ++j) vg[j] = vb[v_goff + (size_t)(t0n + j) * DK];
        }

        // ---- QK^T: sT[qh][kt], 16 MFMA, 8 wave-linear b128 K reads ----
        f32x16 sT[2][2] = {};
        #pragma unroll
        for (int kt = 0; kt < 2; ++kt)
            #pragma unroll
            for (int kd = 0; kd < 4; ++kd) {
                bf16x8 kf = *reinterpret_cast<const bf16x8*>(Kr + kt * 4096 + kd * 1024 + lane * 16);
                sT[0][kt] = __builtin_amdgcn_mfma_f32_32x32x16_bf16(kf, qf[0][kd], sT[0][kt], 0, 0, 0);
                sT[1][kt] = __builtin_amdgcn_mfma_f32_32x32x16_bf16(kf, qf[1][kd], sT[1][kt], 0, 0, 0);
            }

        // ---- softmax: lane-local max, shfl_xor cross-half, defer-max ----
        float mx[2];
        int need = 0;
        #pragma unroll
        for (int qh = 0; qh < 2; ++qh) {
            float m = sT[qh][0][0];
            #pragma unroll
            for (int kt = 0; kt < 2; ++kt)
                #pragma unroll
                for (int i = 0; i < 16; ++i) m = fmaxf(m, sT[qh][kt][i]);
            m = fmaxf(m, __shfl_xor(m, 32));
            mx[qh] = m;
            need |= (m > m_run[qh] + THR) ? 1 : 0;
        }
        if (__any(need)) {
            #pragma unroll
            for (int qh = 0; qh < 2; ++qh) {
                float mn = fmaxf(m_run[qh], mx[qh]);
                float al = exp2_fast(m_run[qh] - mn);
                m_run[qh] = mn;
                l_run[qh] *= al;
                oaccT[qh][0] *= al;
                oaccT[qh][1] *= al;
            }
        }
        // p = exp2(sc - m) in place; 4-way split row sums
        #pragma unroll
        for (int qh = 0; qh < 2; ++qh) {
            float rs0 = 0.f, rs1 = 0.f, rs2 = 0.f, rs3 = 0.f;
            #pragma unroll
            for (int kt = 0; kt < 2; ++kt)
                #pragma unroll
                for (int i = 0; i < 16; i += 4) {
                    float p0 = exp2_fast(sT[qh][kt][i + 0] - m_run[qh]);
                    float p1 = exp2_fast(sT[qh][kt][i + 1] - m_run[qh]);
                    float p2 = exp2_fast(sT[qh][kt][i + 2] - m_run[qh]);
                    float p3 = exp2_fast(sT[qh][kt][i + 3] - m_run[qh]);
                    sT[qh][kt][i + 0] = p0; sT[qh][kt][i + 1] = p1;
                    sT[qh][kt][i + 2] = p2; sT[qh][kt][i + 3] = p3;
                    rs0 += p0; rs1 += p1; rs2 += p2; rs3 += p3;
                }
            float rs = (rs0 + rs1) + (rs2 + rs3);
            rs += __shfl_xor(rs, 32);
            l_run[qh] += rs;
        }

        // ---- PV: O^T += V^T . P^T ; 8 wave-linear b128 V reads, 16 MFMA ----
        // B-frag word table (t' base (ks&1)*16 omitted; own packs:
        //   a0=(4hi,4hi+1) a1=(4hi+2,4hi+3) a2=(8+4hi,9+4hi) a3=(10+4hi,11+4hi)):
        //   needed  hi=0: w={(0,1),(2,3),(4,5),(6,7)}   = {a0, a1, z0, z1}
        //           hi=1: w={(8,9),(10,11),(12,13),(14,15)} = {z0, z1, a2, a3}
        // where z0 = shfl_xor(hi? a0 : a2, 32), z1 = shfl_xor(hi? a1 : a3, 32).
        #pragma unroll
        for (int ks = 0; ks < 4; ++ks) {
            bf16x8 vfA0 = *reinterpret_cast<const bf16x8*>(Vr + ks * 2048 + hi * 1024 + tl31 * 16);
            bf16x8 vfA1 = *reinterpret_cast<const bf16x8*>(Vr + ks * 2048 + hi * 1024 + 512 + tl31 * 16);
            #pragma unroll
            for (int qh = 0; qh < 2; ++qh) {
                const int kt = ks >> 1, b = (ks & 1) * 8;
                unsigned a0 = cvt_pk_bf16(sT[qh][kt][b + 0], sT[qh][kt][b + 1]);
                unsigned a1 = cvt_pk_bf16(sT[qh][kt][b + 2], sT[qh][kt][b + 3]);
                unsigned a2 = cvt_pk_bf16(sT[qh][kt][b + 4], sT[qh][kt][b + 5]);
                unsigned a3 = cvt_pk_bf16(sT[qh][kt][b + 6], sT[qh][kt][b + 7]);
                unsigned z0 = __shfl_xor(hi ? a0 : a2, 32);
                unsigned z1 = __shfl_xor(hi ? a1 : a3, 32);
                u32x4 w;
                w[0] = hi ? z0 : a0;
                w[1] = hi ? z1 : a1;
                w[2] = hi ? a2 : z0;
                w[3] = hi ? a3 : z1;
                bf16x8 pa = __builtin_bit_cast(bf16x8, w);
                oaccT[qh][0] = __builtin_amdgcn_mfma_f32_32x32x16_bf16(vfA0, pa, oaccT[qh][0], 0, 0, 0);
                oaccT[qh][1] = __builtin_amdgcn_mfma_f32_32x32x16_bf16(vfA1, pa, oaccT[qh][1], 0, 0, 0);
            }
        }

        // ---- write next tile to other buffer, single barrier ----
        if (t < 31) {
            char* Kw = lds + (cur ^ 1) * 16384;
            *reinterpret_cast<u16x8*>(Kw + tid * 16) = knext;
            u16x8 vv;
            #pragma unroll
            for (int j = 0; j < 8; ++j) vv[j] = vg[j];
            *reinterpret_cast<u16x8*>(Kw + 8192 + tid * 16) = vv;
        }
        __syncthreads();
    }

    // ---- epilogue: per-wave LDS transpose (O^T -> O), coalesced stores ----
    char* myregion = lds + wave * 4096;   // 32 rows x 128 B, swizzled
    const int bb = bh >> 4, h = bh & 15;
    #pragma unroll
    for (int qh = 0; qh < 2; ++qh) {
        float rl = 1.0f / l_run[qh];
        #pragma unroll
        for (int dh = 0; dh < 2; ++dh)
            #pragma unroll
            for (int r = 0; r < 16; ++r) {
                int dl = (r & 3) + 8 * (r >> 2) + 4 * hi + 32 * dh;
                int boff = (tl31 * 128 + dl * 2) ^ ((tl31 & 7) << 4);
                *reinterpret_cast<unsigned short*>(myregion + boff) =
                    f32_to_bf16_u(oaccT[qh][dh][r] * rl);
            }
        #pragma unroll
        for (int c = 0; c < 4; ++c) {
            int chunk = lane + c * 64;         // 0..255
            int row = chunk >> 3, c16 = chunk & 7;
            int boff = (row * 128 + c16 * 16) ^ ((row & 7) << 4);
            u16x8 v = *reinterpret_cast<const u16x8*>(myregion + boff);
            size_t tok = (size_t)(bb * SEQ) + q0 + wave * 64 + qh * 32 + row;
            *reinterpret_cast<u16x8*>(ob + tok * D_MODEL + h * DK + c16 * 8) = v;
        }
    }
}

extern "C" void kernel_launch(void* const* d_in, const int* in_sizes, int n_in,
                              void* d_out, int out_size, void* d_ws, size_t ws_size,
                              hipStream_t stream)
{
    const float* Q  = (const float*)d_in[0];
    const float* K_ = (const float*)d_in[1];
    const float* V  = (const float*)d_in[2];
    const float* Wq = (const float*)d_in[3];
    const float* bq = (const float*)d_in[4];
    const float* Wk = (const float*)d_in[5];
    const float* bk = (const float*)d_in[6];
    const float* Wv = (const float*)d_in[7];
    const float* bv = (const float*)d_in[8];
    const float* Wo = (const float*)d_in[9];
    const float* bo = (const float*)d_in[10];
    float* out = (float*)d_out;

    const size_t SZ = (size_t)M_TOK * D_MODEL;  // elements
    unsigned short* qh = (unsigned short*)d_ws;  // [B,H,S,DK] bf16
    unsigned short* kh = qh + SZ;
    unsigned short* vh = kh + SZ;
    unsigned short* ah = vh + SZ;                // [B*S, D_MODEL] bf16

    // Q projection pre-scaled by (1/sqrt(DK)) * log2(e) -> softmax in exp2 domain
    const float qscale = 0.125f * 1.4426950408889634f;

    dim3 gg(D_MODEL / 128, M_TOK / 128);
    gemm_nt<false, true><<<gg, 256, 0, stream>>>(Q,  Wq, bq, qh, qscale);
    gemm_nt<false, true><<<gg, 256, 0, stream>>>(K_, Wk, bk, kh, 1.0f);
    gemm_nt<false, true><<<gg, 256, 0, stream>>>(V,  Wv, bv, vh, 1.0f);
    attn_kernel<<<dim3(SEQ / 512, BATCH * NH), 512, 0, stream>>>(qh, kh, vh, ah);
    gemm_nt<true, false><<<gg, 256, 0, stream>>>(ah, Wo, bo, out, 1.0f);
}

// Round 7
// 224.356 us; speedup vs baseline: 2.1476x; 1.1927x over previous
//
#include <hip/hip_runtime.h>
#include <hip/hip_bf16.h>

typedef float  f32x4  __attribute__((ext_vector_type(4)));
typedef float  f32x16 __attribute__((ext_vector_type(16)));
typedef float  fvec4  __attribute__((ext_vector_type(4)));
typedef __bf16 bf16x8 __attribute__((ext_vector_type(8)));
typedef unsigned short u16x8 __attribute__((ext_vector_type(8)));
typedef unsigned int   u32x4 __attribute__((ext_vector_type(4)));

#define DEVINL __device__ __forceinline__

constexpr int D_MODEL = 1024;
constexpr int NH      = 16;
constexpr int DK      = 64;
constexpr int SEQ     = 2048;
constexpr int BATCH   = 4;
constexpr int M_TOK   = BATCH * SEQ;   // 8192

DEVINL unsigned short f32_to_bf16_u(float f) {
    unsigned int u = __builtin_bit_cast(unsigned int, f);
    u = (u + 0x7FFFu + ((u >> 16) & 1u)) >> 16;
    return (unsigned short)u;
}

DEVINL float exp2_fast(float x) { return __builtin_amdgcn_exp2f(x); }

DEVINL unsigned cvt_pk_bf16(float lo, float hi_) {
    unsigned d;
    asm("v_cvt_pk_bf16_f32 %0, %1, %2" : "=v"(d) : "v"(lo), "v"(hi_));
    return d;
}

DEVINL void gload_lds16(const void* g, void* l) {
    __builtin_amdgcn_global_load_lds(
        (const __attribute__((address_space(1))) void*)g,
        (__attribute__((address_space(3))) void*)l, 16, 0, 0);
}

// ---------------------------------------------------------------------------
// fp32 -> bf16 convert (weights), vectorized, memory-bound
// ---------------------------------------------------------------------------
__global__ __launch_bounds__(256) void cvt_bf16(const float* __restrict__ src,
                                                unsigned short* __restrict__ dst,
                                                int n8)
{
    int i = blockIdx.x * 256 + threadIdx.x;
    if (i >= n8) return;
    fvec4 v0 = *reinterpret_cast<const fvec4*>(src + (size_t)i * 8);
    fvec4 v1 = *reinterpret_cast<const fvec4*>(src + (size_t)i * 8 + 4);
    bf16x8 o;
    #pragma unroll
    for (int j = 0; j < 4; ++j) { o[j] = (__bf16)v0[j]; o[j + 4] = (__bf16)v1[j]; }
    *reinterpret_cast<bf16x8*>(dst + (size_t)i * 8) = o;
}

// ---------------------------------------------------------------------------
// NT GEMM: C[m,n] = (sum_k A[m,k]*W[n,k] + bias[n]) * s.  W is bf16.
// A fp32 (reg-staged + cvt_pk into swizzled LDS) or bf16 (global_load_lds,
// linear LDS).  B always global_load_lds, linear LDS (2-phase structure:
// ds-read conflicts are off the critical path, T2-gate).
// 128x128 tile, BK=64, 4 waves, 16x16x32 MFMA, 1D grid + XCD swizzle.
// ---------------------------------------------------------------------------
template<bool A_BF16, bool SPLIT_HEADS>
__global__ __launch_bounds__(256) void gemm_nt(const void* __restrict__ Ap,
                                               const unsigned short* __restrict__ Wb,
                                               const float* __restrict__ bias,
                                               void* __restrict__ outp,
                                               float out_scale)
{
    constexpr int K = D_MODEL, N = D_MODEL;
    __shared__ char As_[128 * 64 * 2];   // 16 KB
    __shared__ char Bs_[128 * 64 * 2];   // 16 KB

    const int tid  = threadIdx.x;
    const int lane = tid & 63;
    const int wave = tid >> 6;
    const int wr = (wave >> 1) * 64;
    const int wc = (wave & 1) * 64;
    // XCD-bijective swizzle (512 wg, 512%8==0): consecutive wg per XCD
    const int wg = ((int)blockIdx.x & 7) * 64 + ((int)blockIdx.x >> 3);
    const int n0 = (wg & 7) * 128;
    const int m0 = (wg >> 3) * 128;
    const int l15 = lane & 15, h16 = lane >> 4;

    f32x4 acc[4][4] = {};

    for (int kt = 0; kt < K; kt += 64) {
        __syncthreads();   // previous tile's reads done before overwrite
        // ---- stage B (bf16 weights) via global_load_lds, linear ----
        #pragma unroll
        for (int i = 0; i < 4; ++i) {
            int chunk = tid + i * 256;
            int r = chunk >> 3, c16 = chunk & 7;
            gload_lds16(Wb + (size_t)(n0 + r) * K + kt + c16 * 8, Bs_ + chunk * 16);
        }
        // ---- stage A ----
        #pragma unroll
        for (int i = 0; i < 4; ++i) {
            int chunk = tid + i * 256;
            int r = chunk >> 3, c16 = chunk & 7;
            if constexpr (A_BF16) {
                gload_lds16((const unsigned short*)Ap + (size_t)(m0 + r) * K + kt + c16 * 8,
                            As_ + chunk * 16);
            } else {
                const float* src = (const float*)Ap + (size_t)(m0 + r) * K + kt + c16 * 8;
                fvec4 v0 = *reinterpret_cast<const fvec4*>(src);
                fvec4 v1 = *reinterpret_cast<const fvec4*>(src + 4);
                bf16x8 o;
                #pragma unroll
                for (int j = 0; j < 4; ++j) { o[j] = (__bf16)v0[j]; o[j + 4] = (__bf16)v1[j]; }
                int boff = (chunk * 16) ^ ((r & 7) << 4);
                *reinterpret_cast<bf16x8*>(As_ + boff) = o;
            }
        }
        __syncthreads();   // compiler drains vmcnt (incl. gload_lds) here

        #pragma unroll
        for (int kk = 0; kk < 2; ++kk) {
            bf16x8 af[4], bfr[4];
            #pragma unroll
            for (int mi = 0; mi < 4; ++mi) {
                int r = wr + mi * 16 + l15;
                int boff = r * 128 + kk * 64 + h16 * 16;
                if constexpr (!A_BF16) boff ^= (r & 7) << 4;
                af[mi] = *reinterpret_cast<const bf16x8*>(As_ + boff);
            }
            #pragma unroll
            for (int ni = 0; ni < 4; ++ni) {
                int r = wc + ni * 16 + l15;
                bfr[ni] = *reinterpret_cast<const bf16x8*>(Bs_ + r * 128 + kk * 64 + h16 * 16);
            }
            #pragma unroll
            for (int mi = 0; mi < 4; ++mi)
                #pragma unroll
                for (int ni = 0; ni < 4; ++ni)
                    acc[mi][ni] = __builtin_amdgcn_mfma_f32_16x16x32_bf16(
                        af[mi], bfr[ni], acc[mi][ni], 0, 0, 0);
        }
    }

    const int rl = h16 * 4;
    #pragma unroll
    for (int mi = 0; mi < 4; ++mi) {
        #pragma unroll
        for (int ni = 0; ni < 4; ++ni) {
            int col = n0 + wc + ni * 16 + l15;
            float bv = bias[col];
            #pragma unroll
            for (int r = 0; r < 4; ++r) {
                int row = m0 + wr + mi * 16 + rl + r;
                float v = (acc[mi][ni][r] + bv) * out_scale;
                if constexpr (SPLIT_HEADS) {
                    int bb = row >> 11, s = row & (SEQ - 1);
                    int h = col >> 6, dk = col & (DK - 1);
                    ((unsigned short*)outp)[((((size_t)bb * NH + h) * SEQ) + s) * DK + dk]
                        = f32_to_bf16_u(v);
                } else {
                    ((float*)outp)[(size_t)row * N + col] = v;
                }
            }
        }
    }
}

// ---------------------------------------------------------------------------
// Flash attention, swapped-QK^T in-register softmax.
// 1D grid 512 blocks (XCD-swizzled: same-head q-blocks share K/V in XCD L2),
// 512 thr = 8 waves, each wave 32 q-rows -> 2 blocks/CU.
// 32x32x16 MFMA; softmax lane-local + one __shfl_xor(32) combine.
// K/V staged frag-contiguous (all ds_read_b128 wave-linear, 0 conflicts);
// V transposed at gather; double-buffered LDS, loads issued early (T14);
// defer-max THR=11 (log2 domain); Q pre-scaled by 0.125*log2(e).
// ---------------------------------------------------------------------------
__global__ __launch_bounds__(512, 4) void attn_kernel(const unsigned short* __restrict__ qb,
                                                      const unsigned short* __restrict__ kb,
                                                      const unsigned short* __restrict__ vb,
                                                      unsigned short* __restrict__ ob)
{
    constexpr float THR = 11.0f;
    __shared__ char lds[32768];   // [2 bufs][K 8KB | V 8KB]

    const int tid  = threadIdx.x;
    const int lane = tid & 63;
    const int tl31 = lane & 31;
    const int hi   = lane >> 5;
    const int wave = tid >> 6;
    const int wg   = ((int)blockIdx.x & 7) * 64 + ((int)blockIdx.x >> 3);
    const int bh   = wg >> 3;
    const int q0   = (wg & 7) * 256;
    const size_t base = (size_t)bh * SEQ * DK;

    const int k_kt = tid >> 8, k_kd = (tid >> 6) & 3, k_hi = (tid >> 5) & 1, k_tl = tid & 31;
    const size_t k_goff = base + (size_t)(k_kt * 32 + k_tl) * DK + k_kd * 16 + k_hi * 8;
    const int v_tg = tid >> 6, v_dh = (tid >> 5) & 1, v_dl = tid & 31;
    const size_t v_goff = base + (size_t)(v_tg * 8) * DK + v_dh * 32 + v_dl;

    // Q fragments: B-operand, col=lane&31=q, k = kd*16 + hi*8 + j
    bf16x8 qf[4];
    #pragma unroll
    for (int kd = 0; kd < 4; ++kd)
        qf[kd] = *reinterpret_cast<const bf16x8*>(
            qb + base + (size_t)(q0 + wave * 32 + tl31) * DK + kd * 16 + hi * 8);

    f32x16 oaccT[2] = {};      // [dh], col=q, row=crow(r,hi)=d
    float m_run = -1e30f, l_run = 0.f;

    {
        u16x8 kreg = *reinterpret_cast<const u16x8*>(kb + k_goff);
        unsigned short vg[8];
        #pragma unroll
        for (int j = 0; j < 8; ++j) vg[j] = vb[v_goff + (size_t)j * DK];
        *reinterpret_cast<u16x8*>(lds + tid * 16) = kreg;
        u16x8 vv;
        #pragma unroll
        for (int j = 0; j < 8; ++j) vv[j] = vg[j];
        *reinterpret_cast<u16x8*>(lds + 8192 + tid * 16) = vv;
    }
    __syncthreads();

    for (int t = 0; t < 32; ++t) {
        const int cur = t & 1;
        const char* Kr = lds + cur * 16384;
        const char* Vr = Kr + 8192;

        u16x8 knext;
        unsigned short vg[8];
        if (t < 31) {
            const int t0n = (t + 1) * 64;
            knext = *reinterpret_cast<const u16x8*>(kb + k_goff + (size_t)t0n * DK);
            #pragma unroll
            for (int j = 0; j < 8; ++j) vg[j] = vb[v_goff + (size_t)(t0n + j) * DK];
        }

        // ---- QK^T: 8 MFMA, 8 wave-linear b128 K reads ----
        f32x16 sT[2] = {};
        #pragma unroll
        for (int kt = 0; kt < 2; ++kt)
            #pragma unroll
            for (int kd = 0; kd < 4; ++kd) {
                bf16x8 kf = *reinterpret_cast<const bf16x8*>(Kr + kt * 4096 + kd * 1024 + lane * 16);
                sT[kt] = __builtin_amdgcn_mfma_f32_32x32x16_bf16(kf, qf[kd], sT[kt], 0, 0, 0);
            }

        // ---- softmax: lane-local max, shfl_xor cross-half, defer-max ----
        float m = sT[0][0];
        #pragma unroll
        for (int kt = 0; kt < 2; ++kt)
            #pragma unroll
            for (int i = 0; i < 16; ++i) m = fmaxf(m, sT[kt][i]);
        m = fmaxf(m, __shfl_xor(m, 32));
        if (__any(m > m_run + THR)) {
            float mn = fmaxf(m_run, m);
            float al = exp2_fast(m_run - mn);
            m_run = mn;
            l_run *= al;
            oaccT[0] *= al;
            oaccT[1] *= al;
        }
        {
            float rs0 = 0.f, rs1 = 0.f, rs2 = 0.f, rs3 = 0.f;
            #pragma unroll
            for (int kt = 0; kt < 2; ++kt)
                #pragma unroll
                for (int i = 0; i < 16; i += 4) {
                    float p0 = exp2_fast(sT[kt][i + 0] - m_run);
                    float p1 = exp2_fast(sT[kt][i + 1] - m_run);
                    float p2 = exp2_fast(sT[kt][i + 2] - m_run);
                    float p3 = exp2_fast(sT[kt][i + 3] - m_run);
                    sT[kt][i + 0] = p0; sT[kt][i + 1] = p1;
                    sT[kt][i + 2] = p2; sT[kt][i + 3] = p3;
                    rs0 += p0; rs1 += p1; rs2 += p2; rs3 += p3;
                }
            float rs = (rs0 + rs1) + (rs2 + rs3);
            rs += __shfl_xor(rs, 32);
            l_run += rs;
        }

        // ---- PV: O^T += V^T . P^T ; 8 wave-linear b128 V reads, 8 MFMA ----
        //   needed  hi=0: w={a0,a1,z0,z1}   hi=1: w={z0,z1,a2,a3}
        //   z0 = shfl_xor(hi? a0 : a2, 32), z1 = shfl_xor(hi? a1 : a3, 32)
        #pragma unroll
        for (int ks = 0; ks < 4; ++ks) {
            bf16x8 vfA0 = *reinterpret_cast<const bf16x8*>(Vr + ks * 2048 + hi * 1024 + tl31 * 16);
            bf16x8 vfA1 = *reinterpret_cast<const bf16x8*>(Vr + ks * 2048 + hi * 1024 + 512 + tl31 * 16);
            const int kt = ks >> 1, b = (ks & 1) * 8;
            unsigned a0 = cvt_pk_bf16(sT[kt][b + 0], sT[kt][b + 1]);
            unsigned a1 = cvt_pk_bf16(sT[kt][b + 2], sT[kt][b + 3]);
            unsigned a2 = cvt_pk_bf16(sT[kt][b + 4], sT[kt][b + 5]);
            unsigned a3 = cvt_pk_bf16(sT[kt][b + 6], sT[kt][b + 7]);
            unsigned z0 = __shfl_xor(hi ? a0 : a2, 32);
            unsigned z1 = __shfl_xor(hi ? a1 : a3, 32);
            u32x4 w;
            w[0] = hi ? z0 : a0;
            w[1] = hi ? z1 : a1;
            w[2] = hi ? a2 : z0;
            w[3] = hi ? a3 : z1;
            bf16x8 pa = __builtin_bit_cast(bf16x8, w);
            oaccT[0] = __builtin_amdgcn_mfma_f32_32x32x16_bf16(vfA0, pa, oaccT[0], 0, 0, 0);
            oaccT[1] = __builtin_amdgcn_mfma_f32_32x32x16_bf16(vfA1, pa, oaccT[1], 0, 0, 0);
        }

        if (t < 31) {
            char* Kw = lds + (cur ^ 1) * 16384;
            *reinterpret_cast<u16x8*>(Kw + tid * 16) = knext;
            u16x8 vv;
            #pragma unroll
            for (int j = 0; j < 8; ++j) vv[j] = vg[j];
            *reinterpret_cast<u16x8*>(Kw + 8192 + tid * 16) = vv;
        }
        __syncthreads();
    }

    // ---- epilogue: per-wave LDS transpose (O^T -> O), coalesced stores ----
    char* myregion = lds + wave * 4096;   // 32 rows x 128 B, swizzled
    const int bb = bh >> 4, h = bh & 15;
    {
        float rl = 1.0f / l_run;
        #pragma unroll
        for (int dh = 0; dh < 2; ++dh)
            #pragma unroll
            for (int r = 0; r < 16; ++r) {
                int dl = (r & 3) + 8 * (r >> 2) + 4 * hi + 32 * dh;
                int boff = (tl31 * 128 + dl * 2) ^ ((tl31 & 7) << 4);
                *reinterpret_cast<unsigned short*>(myregion + boff) =
                    f32_to_bf16_u(oaccT[dh][r] * rl);
            }
        #pragma unroll
        for (int c = 0; c < 4; ++c) {
            int chunk = lane + c * 64;
            int row = chunk >> 3, c16 = chunk & 7;
            int boff = (row * 128 + c16 * 16) ^ ((row & 7) << 4);
            u16x8 v = *reinterpret_cast<const u16x8*>(myregion + boff);
            size_t tok = (size_t)(bb * SEQ) + q0 + wave * 32 + row;
            *reinterpret_cast<u16x8*>(ob + tok * D_MODEL + h * DK + c16 * 8) = v;
        }
    }
}

extern "C" void kernel_launch(void* const* d_in, const int* in_sizes, int n_in,
                              void* d_out, int out_size, void* d_ws, size_t ws_size,
                              hipStream_t stream)
{
    const float* Q  = (const float*)d_in[0];
    const float* K_ = (const float*)d_in[1];
    const float* V  = (const float*)d_in[2];
    const float* Wq = (const float*)d_in[3];
    const float* bq = (const float*)d_in[4];
    const float* Wk = (const float*)d_in[5];
    const float* bk = (const float*)d_in[6];
    const float* Wv = (const float*)d_in[7];
    const float* bv = (const float*)d_in[8];
    const float* Wo = (const float*)d_in[9];
    const float* bo = (const float*)d_in[10];
    float* out = (float*)d_out;

    const size_t SZ = (size_t)M_TOK * D_MODEL;   // 8M elements
    const size_t WZ = (size_t)D_MODEL * D_MODEL; // 1M elements
    unsigned short* qh_ = (unsigned short*)d_ws; // [B,H,S,DK] bf16
    unsigned short* kh_ = qh_ + SZ;
    unsigned short* vh_ = kh_ + SZ;
    unsigned short* ah_ = vh_ + SZ;              // [B*S, D_MODEL] bf16
    unsigned short* wqb = ah_ + SZ;              // bf16 weights
    unsigned short* wkb = wqb + WZ;
    unsigned short* wvb = wkb + WZ;
    unsigned short* wob = wvb + WZ;

    const float qscale = 0.125f * 1.4426950408889634f;  // exp2-domain softmax

    const int cvtg = (int)(WZ / 8 / 256);  // 512 blocks
    cvt_bf16<<<cvtg, 256, 0, stream>>>(Wq, wqb, (int)(WZ / 8));
    cvt_bf16<<<cvtg, 256, 0, stream>>>(Wk, wkb, (int)(WZ / 8));
    cvt_bf16<<<cvtg, 256, 0, stream>>>(Wv, wvb, (int)(WZ / 8));
    cvt_bf16<<<cvtg, 256, 0, stream>>>(Wo, wob, (int)(WZ / 8));

    gemm_nt<false, true><<<512, 256, 0, stream>>>(Q,  wqb, bq, qh_, qscale);
    gemm_nt<false, true><<<512, 256, 0, stream>>>(K_, wkb, bk, kh_, 1.0f);
    gemm_nt<false, true><<<512, 256, 0, stream>>>(V,  wvb, bv, vh_, 1.0f);
    attn_kernel<<<512, 512, 0, stream>>>(qh_, kh_, vh_, ah_);
    gemm_nt<true, false><<<512, 256, 0, stream>>>(ah_, wob, bo, out, 1.0f);
}

// Round 10
// 217.767 us; speedup vs baseline: 2.2125x; 1.0303x over previous
//
#include <hip/hip_runtime.h>
#include <hip/hip_bf16.h>

typedef float  f32x4  __attribute__((ext_vector_type(4)));
typedef float  f32x16 __attribute__((ext_vector_type(16)));
typedef float  fvec4  __attribute__((ext_vector_type(4)));
typedef __bf16 bf16x8 __attribute__((ext_vector_type(8)));
typedef unsigned short u16x4 __attribute__((ext_vector_type(4)));
typedef unsigned short u16x8 __attribute__((ext_vector_type(8)));
typedef unsigned int   u32x4 __attribute__((ext_vector_type(4)));

#define DEVINL __device__ __forceinline__

constexpr int D_MODEL = 1024;
constexpr int NH      = 16;
constexpr int DK      = 64;
constexpr int SEQ     = 2048;
constexpr int BATCH   = 4;
constexpr int M_TOK   = BATCH * SEQ;   // 8192

DEVINL unsigned short f32_to_bf16_u(float f) {
    unsigned int u = __builtin_bit_cast(unsigned int, f);
    u = (u + 0x7FFFu + ((u >> 16) & 1u)) >> 16;
    return (unsigned short)u;
}

DEVINL float exp2_fast(float x) { return __builtin_amdgcn_exp2f(x); }

DEVINL unsigned cvt_pk_bf16(float lo, float hi_) {
    unsigned d;
    asm("v_cvt_pk_bf16_f32 %0, %1, %2" : "=v"(d) : "v"(lo), "v"(hi_));
    return d;
}

DEVINL void gload_lds16(const void* g, void* l) {
    __builtin_amdgcn_global_load_lds(
        (const __attribute__((address_space(1))) void*)g,
        (__attribute__((address_space(3))) void*)l, 16, 0, 0);
}

// ---------------------------------------------------------------------------
// fused fp32 -> bf16 converts: 4 weight matrices / 3 input tensors.
// ---------------------------------------------------------------------------
__global__ __launch_bounds__(256) void cvt4(const float* __restrict__ a,
                                            const float* __restrict__ b,
                                            const float* __restrict__ c,
                                            const float* __restrict__ d,
                                            unsigned short* __restrict__ dst, int n8)
{
    int y = blockIdx.y;
    const float* s = (y == 0) ? a : (y == 1) ? b : (y == 2) ? c : d;
    size_t i = blockIdx.x * 256 + threadIdx.x;
    fvec4 v0 = *reinterpret_cast<const fvec4*>(s + i * 8);
    fvec4 v1 = *reinterpret_cast<const fvec4*>(s + i * 8 + 4);
    bf16x8 o;
    #pragma unroll
    for (int j = 0; j < 4; ++j) { o[j] = (__bf16)v0[j]; o[j + 4] = (__bf16)v1[j]; }
    *reinterpret_cast<bf16x8*>(dst + ((size_t)y * n8 + i) * 8) = o;
}

__global__ __launch_bounds__(256) void cvt3(const float* __restrict__ a,
                                            const float* __restrict__ b,
                                            const float* __restrict__ c,
                                            unsigned short* __restrict__ dst, int n8)
{
    int y = blockIdx.y;
    const float* s = (y == 0) ? a : (y == 1) ? b : c;
    size_t i = blockIdx.x * 256 + threadIdx.x;
    fvec4 v0 = *reinterpret_cast<const fvec4*>(s + i * 8);
    fvec4 v1 = *reinterpret_cast<const fvec4*>(s + i * 8 + 4);
    bf16x8 o;
    #pragma unroll
    for (int j = 0; j < 4; ++j) { o[j] = (__bf16)v0[j]; o[j + 4] = (__bf16)v1[j]; }
    *reinterpret_cast<bf16x8*>(dst + ((size_t)y * n8 + i) * 8) = o;
}

// ---------------------------------------------------------------------------
// NT GEMM (unchanged from R9; m97-proven 2-barrier stage/compute).
// OMODE: 0 = fp32 [M,N]; 1 = bf16 [B,H,S,DK]; 2 = bf16 [B,H,DK,S] (V^T).
// ---------------------------------------------------------------------------
template<bool A_BF16, int OMODE>
__global__ __launch_bounds__(256) void gemm_nt(const void* __restrict__ Ap,
                                               const unsigned short* __restrict__ Wb,
                                               const float* __restrict__ bias,
                                               void* __restrict__ outp,
                                               float out_scale)
{
    constexpr int K = D_MODEL, N = D_MODEL;
    __shared__ char As_[128 * 64 * 2];   // 16 KB
    __shared__ char Bs_[128 * 64 * 2];   // 16 KB

    const int tid  = threadIdx.x;
    const int lane = tid & 63;
    const int wave = tid >> 6;
    const int wr = (wave >> 1) * 64;
    const int wc = (wave & 1) * 64;
    const int wg = ((int)blockIdx.x & 7) * 64 + ((int)blockIdx.x >> 3);
    const int n0 = (wg & 7) * 128;
    const int m0 = (wg >> 3) * 128;
    const int l15 = lane & 15, h16 = lane >> 4;

    f32x4 acc[4][4] = {};

    for (int kt = 0; kt < K; kt += 64) {
        __syncthreads();   // previous tile's reads done before overwrite
        #pragma unroll
        for (int i = 0; i < 4; ++i) {
            int chunk = tid + i * 256;
            int r = chunk >> 3, c16 = chunk & 7;
            int cs = (c16 ^ (r & 7)) * 8;        // pre-swizzled source column
            gload_lds16(Wb + (size_t)(n0 + r) * K + kt + cs, Bs_ + chunk * 16);
            if constexpr (A_BF16) {
                gload_lds16((const unsigned short*)Ap + (size_t)(m0 + r) * K + kt + cs,
                            As_ + chunk * 16);
            } else {
                const float* src = (const float*)Ap + (size_t)(m0 + r) * K + kt + c16 * 8;
                fvec4 v0 = *reinterpret_cast<const fvec4*>(src);
                fvec4 v1 = *reinterpret_cast<const fvec4*>(src + 4);
                bf16x8 o;
                #pragma unroll
                for (int j = 0; j < 4; ++j) { o[j] = (__bf16)v0[j]; o[j + 4] = (__bf16)v1[j]; }
                *reinterpret_cast<bf16x8*>(As_ + ((chunk * 16) ^ ((r & 7) << 4))) = o;
            }
        }
        __syncthreads();   // drains vmcnt (incl. gload_lds)

        #pragma unroll
        for (int kk = 0; kk < 2; ++kk) {
            bf16x8 af[4], bfr[4];
            #pragma unroll
            for (int mi = 0; mi < 4; ++mi) {
                int r = wr + mi * 16 + l15;
                af[mi] = *reinterpret_cast<const bf16x8*>(
                    As_ + ((r * 128 + kk * 64 + h16 * 16) ^ ((r & 7) << 4)));
            }
            #pragma unroll
            for (int ni = 0; ni < 4; ++ni) {
                int r = wc + ni * 16 + l15;
                bfr[ni] = *reinterpret_cast<const bf16x8*>(
                    Bs_ + ((r * 128 + kk * 64 + h16 * 16) ^ ((r & 7) << 4)));
            }
            #pragma unroll
            for (int mi = 0; mi < 4; ++mi)
                #pragma unroll
                for (int ni = 0; ni < 4; ++ni)
                    acc[mi][ni] = __builtin_amdgcn_mfma_f32_16x16x32_bf16(
                        af[mi], bfr[ni], acc[mi][ni], 0, 0, 0);
        }
    }

    const int rl = h16 * 4;
    #pragma unroll
    for (int mi = 0; mi < 4; ++mi) {
        #pragma unroll
        for (int ni = 0; ni < 4; ++ni) {
            int col = n0 + wc + ni * 16 + l15;
            float bv = bias[col];
            if constexpr (OMODE == 2) {
                int row0 = m0 + wr + mi * 16 + rl;
                int bb = row0 >> 11, s0 = row0 & (SEQ - 1);
                int h = col >> 6, dk = col & (DK - 1);
                u16x4 o;
                #pragma unroll
                for (int r = 0; r < 4; ++r)
                    o[r] = f32_to_bf16_u((acc[mi][ni][r] + bv) * out_scale);
                *reinterpret_cast<u16x4*>((unsigned short*)outp +
                    (((size_t)bb * NH + h) * DK + dk) * SEQ + s0) = o;
            } else {
                #pragma unroll
                for (int r = 0; r < 4; ++r) {
                    int row = m0 + wr + mi * 16 + rl + r;
                    float v = (acc[mi][ni][r] + bv) * out_scale;
                    if constexpr (OMODE == 1) {
                        int bb = row >> 11, s = row & (SEQ - 1);
                        int h = col >> 6, dk = col & (DK - 1);
                        ((unsigned short*)outp)[((((size_t)bb * NH + h) * SEQ) + s) * DK + dk]
                            = f32_to_bf16_u(v);
                    } else {
                        ((float*)outp)[(size_t)row * N + col] = v;
                    }
                }
            }
        }
    }
}

// ---------------------------------------------------------------------------
// Flash attention, swapped-QK^T in-register softmax.
// STAGING REVERTED to the R7-PROVEN template after R9's replay race:
//   reg-load next tile (issued before compute, T14) -> compute buf[cur] ->
//   ds_write_b128 into buf[cur^1] -> ONE barrier.  gload_lds-into-dbuf with a
//   single barrier raced across graph replays (R9); this template passed
//   twice (R6/R7).  With V pre-transposed ([B,H,DK,S]) the reg stage is just
//   2 x 16B vector loads + 2 x ds_write_b128 per thread per tile.
// All ds_read_b128 wave-linear (frag-contiguous chunk order), 0 conflicts.
// Softmax lane-local + one __shfl_xor(32); defer-max THR=11 (log2 domain);
// Q pre-scaled by 0.125*log2(e).  (512,4): never below the live-reg floor.
// ---------------------------------------------------------------------------
__global__ __launch_bounds__(512, 4) void attn_kernel(const unsigned short* __restrict__ qb,
                                                      const unsigned short* __restrict__ kb,
                                                      const unsigned short* __restrict__ vt,
                                                      unsigned short* __restrict__ ob)
{
    constexpr float THR = 11.0f;
    __shared__ char lds[32768];   // [2 bufs][K 8KB | V 8KB]

    const int tid  = threadIdx.x;
    const int lane = tid & 63;
    const int tl31 = lane & 31;
    const int hi   = lane >> 5;
    const int wave = tid >> 6;
    const int wg   = ((int)blockIdx.x & 7) * 64 + ((int)blockIdx.x >> 3);
    const int bh   = wg >> 3;
    const int q0   = (wg & 7) * 256;
    const size_t base  = (size_t)bh * SEQ * DK;   // K: [s][dk]
    const size_t baseT = (size_t)bh * DK * SEQ;   // V^T: [dk][s]

    // K chunk: content K[t0 + kt*32 + ktl][kd*16 + khi*8 + j]
    const int k_kt = tid >> 8, k_kd = (tid >> 6) & 3, k_hi = (tid >> 5) & 1, k_tl = tid & 31;
    const size_t k_goff = base + (size_t)(k_kt * 32 + k_tl) * DK + k_kd * 16 + k_hi * 8;
    // V chunk: content V^T[dh*32 + dl][t0 + tg*8 + j]
    const int v_tg = tid >> 6, v_dh = (tid >> 5) & 1, v_dl = tid & 31;
    const size_t v_goff = baseT + (size_t)(v_dh * 32 + v_dl) * SEQ + v_tg * 8;

    // Q fragments: B-operand, col=lane&31=q, k = kd*16 + hi*8 + j
    bf16x8 qf[4];
    #pragma unroll
    for (int kd = 0; kd < 4; ++kd)
        qf[kd] = *reinterpret_cast<const bf16x8*>(
            qb + base + (size_t)(q0 + wave * 32 + tl31) * DK + kd * 16 + hi * 8);

    f32x16 oaccT[2] = {};      // [dh], col=q, row=crow(r,hi)=d
    float m_run = -1e30f, l_run = 0.f;

    // prologue: reg-load tile 0, write buf 0
    {
        u16x8 kreg = *reinterpret_cast<const u16x8*>(kb + k_goff);
        u16x8 vreg = *reinterpret_cast<const u16x8*>(vt + v_goff);
        *reinterpret_cast<u16x8*>(lds + tid * 16) = kreg;
        *reinterpret_cast<u16x8*>(lds + 8192 + tid * 16) = vreg;
    }
    __syncthreads();

    for (int t = 0; t < 32; ++t) {
        const int cur = t & 1;
        const char* Kr = lds + cur * 16384;
        const char* Vr = Kr + 8192;

        // issue next tile's global loads early (latency hides under compute)
        u16x8 kreg, vreg;
        if (t < 31) {
            const int t0n = (t + 1) * 64;
            kreg = *reinterpret_cast<const u16x8*>(kb + k_goff + (size_t)t0n * DK);
            vreg = *reinterpret_cast<const u16x8*>(vt + v_goff + t0n);
        }

        // ---- QK^T: 8 MFMA, 8 wave-linear b128 K reads ----
        f32x16 sT[2] = {};
        #pragma unroll
        for (int kt = 0; kt < 2; ++kt)
            #pragma unroll
            for (int kd = 0; kd < 4; ++kd) {
                bf16x8 kf = *reinterpret_cast<const bf16x8*>(Kr + kt * 4096 + kd * 1024 + lane * 16);
                sT[kt] = __builtin_amdgcn_mfma_f32_32x32x16_bf16(kf, qf[kd], sT[kt], 0, 0, 0);
            }

        // ---- softmax: lane-local max, shfl_xor cross-half, defer-max ----
        float m = sT[0][0];
        #pragma unroll
        for (int kt = 0; kt < 2; ++kt)
            #pragma unroll
            for (int i = 0; i < 16; ++i) m = fmaxf(m, sT[kt][i]);
        m = fmaxf(m, __shfl_xor(m, 32));
        if (__any(m > m_run + THR)) {
            float mn = fmaxf(m_run, m);
            float al = exp2_fast(m_run - mn);
            m_run = mn;
            l_run *= al;
            oaccT[0] *= al;
            oaccT[1] *= al;
        }
        {
            float rs0 = 0.f, rs1 = 0.f, rs2 = 0.f, rs3 = 0.f;
            #pragma unroll
            for (int kt = 0; kt < 2; ++kt)
                #pragma unroll
                for (int i = 0; i < 16; i += 4) {
                    float p0 = exp2_fast(sT[kt][i + 0] - m_run);
                    float p1 = exp2_fast(sT[kt][i + 1] - m_run);
                    float p2 = exp2_fast(sT[kt][i + 2] - m_run);
                    float p3 = exp2_fast(sT[kt][i + 3] - m_run);
                    sT[kt][i + 0] = p0; sT[kt][i + 1] = p1;
                    sT[kt][i + 2] = p2; sT[kt][i + 3] = p3;
                    rs0 += p0; rs1 += p1; rs2 += p2; rs3 += p3;
                }
            float rs = (rs0 + rs1) + (rs2 + rs3);
            rs += __shfl_xor(rs, 32);
            l_run += rs;
        }

        // ---- PV: O^T += V^T . P^T ; 8 wave-linear b128 V reads, 8 MFMA ----
        //   needed  hi=0: w={a0,a1,z0,z1}   hi=1: w={z0,z1,a2,a3}
        //   z0 = shfl_xor(hi? a0 : a2, 32), z1 = shfl_xor(hi? a1 : a3, 32)
        #pragma unroll
        for (int ks = 0; ks < 4; ++ks) {
            bf16x8 vfA0 = *reinterpret_cast<const bf16x8*>(Vr + ks * 2048 + hi * 1024 + tl31 * 16);
            bf16x8 vfA1 = *reinterpret_cast<const bf16x8*>(Vr + ks * 2048 + hi * 1024 + 512 + tl31 * 16);
            const int kt = ks >> 1, b = (ks & 1) * 8;
            unsigned a0 = cvt_pk_bf16(sT[kt][b + 0], sT[kt][b + 1]);
            unsigned a1 = cvt_pk_bf16(sT[kt][b + 2], sT[kt][b + 3]);
            unsigned a2 = cvt_pk_bf16(sT[kt][b + 4], sT[kt][b + 5]);
            unsigned a3 = cvt_pk_bf16(sT[kt][b + 6], sT[kt][b + 7]);
            unsigned z0 = __shfl_xor(hi ? a0 : a2, 32);
            unsigned z1 = __shfl_xor(hi ? a1 : a3, 32);
            u32x4 w;
            w[0] = hi ? z0 : a0;
            w[1] = hi ? z1 : a1;
            w[2] = hi ? a2 : z0;
            w[3] = hi ? a3 : z1;
            bf16x8 pa = __builtin_bit_cast(bf16x8, w);
            oaccT[0] = __builtin_amdgcn_mfma_f32_32x32x16_bf16(vfA0, pa, oaccT[0], 0, 0, 0);
            oaccT[1] = __builtin_amdgcn_mfma_f32_32x32x16_bf16(vfA1, pa, oaccT[1], 0, 0, 0);
        }

        // ---- write next tile into the other buffer (R7-proven placement) ----
        if (t < 31) {
            char* Kw = lds + (cur ^ 1) * 16384;
            *reinterpret_cast<u16x8*>(Kw + tid * 16) = kreg;
            *reinterpret_cast<u16x8*>(Kw + 8192 + tid * 16) = vreg;
        }
        __syncthreads();
    }

    // ---- epilogue: per-wave LDS transpose (O^T -> O), coalesced stores ----
    char* myregion = lds + wave * 4096;   // 32 rows x 128 B, swizzled
    const int bb = bh >> 4, h = bh & 15;
    {
        float rl = 1.0f / l_run;
        #pragma unroll
        for (int dh = 0; dh < 2; ++dh)
            #pragma unroll
            for (int r = 0; r < 16; ++r) {
                int dl = (r & 3) + 8 * (r >> 2) + 4 * hi + 32 * dh;
                int boff = (tl31 * 128 + dl * 2) ^ ((tl31 & 7) << 4);
                *reinterpret_cast<unsigned short*>(myregion + boff) =
                    f32_to_bf16_u(oaccT[dh][r] * rl);
            }
        #pragma unroll
        for (int c = 0; c < 4; ++c) {
            int chunk = lane + c * 64;
            int row = chunk >> 3, c16 = chunk & 7;
            int boff = (row * 128 + c16 * 16) ^ ((row & 7) << 4);
            u16x8 v = *reinterpret_cast<const u16x8*>(myregion + boff);
            size_t tok = (size_t)(bb * SEQ) + q0 + wave * 32 + row;
            *reinterpret_cast<u16x8*>(ob + tok * D_MODEL + h * DK + c16 * 8) = v;
        }
    }
}

extern "C" void kernel_launch(void* const* d_in, const int* in_sizes, int n_in,
                              void* d_out, int out_size, void* d_ws, size_t ws_size,
                              hipStream_t stream)
{
    const float* Q  = (const float*)d_in[0];
    const float* K_ = (const float*)d_in[1];
    const float* V  = (const float*)d_in[2];
    const float* Wq = (const float*)d_in[3];
    const float* bq = (const float*)d_in[4];
    const float* Wk = (const float*)d_in[5];
    const float* bk = (const float*)d_in[6];
    const float* Wv = (const float*)d_in[7];
    const float* bv = (const float*)d_in[8];
    const float* Wo = (const float*)d_in[9];
    const float* bo = (const float*)d_in[10];
    float* out = (float*)d_out;

    const size_t SZ = (size_t)M_TOK * D_MODEL;   // 8M elements
    const size_t WZ = (size_t)D_MODEL * D_MODEL; // 1M elements
    unsigned short* qh_ = (unsigned short*)d_ws; // [B,H,S,DK] bf16
    unsigned short* kh_ = qh_ + SZ;
    unsigned short* vh_ = kh_ + SZ;              // V^T: [B,H,DK,S] bf16
    unsigned short* ah_ = vh_ + SZ;              // [B*S, D_MODEL] bf16
    unsigned short* wqb = ah_ + SZ;              // bf16 weights (contiguous x4)
    unsigned short* wkb = wqb + WZ;
    unsigned short* wvb = wkb + WZ;
    unsigned short* wob = wvb + WZ;
    unsigned short* qbf = wob + WZ;              // bf16 inputs (contiguous x3)
    unsigned short* kbf = qbf + SZ;
    unsigned short* vbf = kbf + SZ;

    const bool big = ws_size >= (size_t)(4 * SZ + 4 * WZ + 3 * SZ) * 2;
    const float qscale = 0.125f * 1.4426950408889634f;  // exp2-domain softmax

    cvt4<<<dim3((int)(WZ / 8 / 256), 4), 256, 0, stream>>>(Wq, Wk, Wv, Wo, wqb, (int)(WZ / 8));

    if (big) {
        cvt3<<<dim3((int)(SZ / 8 / 256), 3), 256, 0, stream>>>(Q, K_, V, qbf, (int)(SZ / 8));
        gemm_nt<true, 1><<<512, 256, 0, stream>>>(qbf, wqb, bq, qh_, qscale);
        gemm_nt<true, 1><<<512, 256, 0, stream>>>(kbf, wkb, bk, kh_, 1.0f);
        gemm_nt<true, 2><<<512, 256, 0, stream>>>(vbf, wvb, bv, vh_, 1.0f);
    } else {
        gemm_nt<false, 1><<<512, 256, 0, stream>>>(Q,  wqb, bq, qh_, qscale);
        gemm_nt<false, 1><<<512, 256, 0, stream>>>(K_, wkb, bk, kh_, 1.0f);
        gemm_nt<false, 2><<<512, 256, 0, stream>>>(V,  wvb, bv, vh_, 1.0f);
    }
    attn_kernel<<<512, 512, 0, stream>>>(qh_, kh_, vh_, ah_);
    gemm_nt<true, 0><<<512, 256, 0, stream>>>(ah_, wob, bo, out, 1.0f);
}

// Round 11
// 203.693 us; speedup vs baseline: 2.3654x; 1.0691x over previous
//
#include <hip/hip_runtime.h>
#include <hip/hip_bf16.h>

typedef float  f32x4  __attribute__((ext_vector_type(4)));
typedef float  f32x16 __attribute__((ext_vector_type(16)));
typedef float  fvec4  __attribute__((ext_vector_type(4)));
typedef __bf16 bf16x8 __attribute__((ext_vector_type(8)));
typedef unsigned short u16x4 __attribute__((ext_vector_type(4)));
typedef unsigned short u16x8 __attribute__((ext_vector_type(8)));
typedef unsigned int   u32x4 __attribute__((ext_vector_type(4)));

#define DEVINL __device__ __forceinline__

constexpr int D_MODEL = 1024;
constexpr int NH      = 16;
constexpr int DK      = 64;
constexpr int SEQ     = 2048;
constexpr int BATCH   = 4;
constexpr int M_TOK   = BATCH * SEQ;   // 8192

DEVINL unsigned short f32_to_bf16_u(float f) {
    unsigned int u = __builtin_bit_cast(unsigned int, f);
    u = (u + 0x7FFFu + ((u >> 16) & 1u)) >> 16;
    return (unsigned short)u;
}

DEVINL float exp2_fast(float x) { return __builtin_amdgcn_exp2f(x); }
DEVINL float mx3(float a, float b, float c) { return fmaxf(fmaxf(a, b), c); }

DEVINL unsigned cvt_pk_bf16(float lo, float hi_) {
    unsigned d;
    asm("v_cvt_pk_bf16_f32 %0, %1, %2" : "=v"(d) : "v"(lo), "v"(hi_));
    return d;
}

DEVINL void gload_lds16(const void* g, void* l) {
    __builtin_amdgcn_global_load_lds(
        (const __attribute__((address_space(1))) void*)g,
        (__attribute__((address_space(3))) void*)l, 16, 0, 0);
}

// s-axis permutation for V^T storage: involution swapping s&15 in {4..7} with
// {8..11}. Makes the PV B-frag lane-local (zero cross-lane exchange): lane
// (q,hi)'s own sT registers are its B-frag words; A-frag (V^T) reads pick up
// the matching rows because LDS holds the permuted order. 4-runs (s0%4==0)
// stay contiguous -> u16x4 store keeps working.
DEVINL int vperm_s(int s0) { return (s0 & ~12) | ((s0 & 4) << 1) | ((s0 & 8) >> 1); }

// ---------------------------------------------------------------------------
// fused fp32 -> bf16 converts: 4 weight matrices / 3 input tensors.
// ---------------------------------------------------------------------------
__global__ __launch_bounds__(256) void cvt4(const float* __restrict__ a,
                                            const float* __restrict__ b,
                                            const float* __restrict__ c,
                                            const float* __restrict__ d,
                                            unsigned short* __restrict__ dst, int n8)
{
    int y = blockIdx.y;
    const float* s = (y == 0) ? a : (y == 1) ? b : (y == 2) ? c : d;
    size_t i = blockIdx.x * 256 + threadIdx.x;
    fvec4 v0 = *reinterpret_cast<const fvec4*>(s + i * 8);
    fvec4 v1 = *reinterpret_cast<const fvec4*>(s + i * 8 + 4);
    bf16x8 o;
    #pragma unroll
    for (int j = 0; j < 4; ++j) { o[j] = (__bf16)v0[j]; o[j + 4] = (__bf16)v1[j]; }
    *reinterpret_cast<bf16x8*>(dst + ((size_t)y * n8 + i) * 8) = o;
}

__global__ __launch_bounds__(256) void cvt3(const float* __restrict__ a,
                                            const float* __restrict__ b,
                                            const float* __restrict__ c,
                                            unsigned short* __restrict__ dst, int n8)
{
    int y = blockIdx.y;
    const float* s = (y == 0) ? a : (y == 1) ? b : c;
    size_t i = blockIdx.x * 256 + threadIdx.x;
    fvec4 v0 = *reinterpret_cast<const fvec4*>(s + i * 8);
    fvec4 v1 = *reinterpret_cast<const fvec4*>(s + i * 8 + 4);
    bf16x8 o;
    #pragma unroll
    for (int j = 0; j < 4; ++j) { o[j] = (__bf16)v0[j]; o[j + 4] = (__bf16)v1[j]; }
    *reinterpret_cast<bf16x8*>(dst + ((size_t)y * n8 + i) * 8) = o;
}

// ---------------------------------------------------------------------------
// NT GEMM, bf16 A via global_load_lds (m97-proven 2-barrier stage/compute).
// QKV=true: grid (512,3); y=0 Q->OMODE1(qscale), y=1 K->OMODE1, y=2 V->OMODE2
// (V^T [B,H,DK,S] with vperm_s s-permutation).  QKV=false: single O-proj,
// fp32 [M,N] output.  128x128 tile, BK=64, pre-swizzled gload source +
// XOR-swizzled frag reads, XCD-bijective 1D swizzle.
// ---------------------------------------------------------------------------
template<bool QKV>
__global__ __launch_bounds__(256) void gemm_bf(
    const unsigned short* __restrict__ A0, const unsigned short* __restrict__ W0,
    const float* __restrict__ B0, void* __restrict__ O0,
    const unsigned short* __restrict__ A1, const unsigned short* __restrict__ W1,
    const float* __restrict__ B1, void* __restrict__ O1,
    const unsigned short* __restrict__ A2, const unsigned short* __restrict__ W2,
    const float* __restrict__ B2, void* __restrict__ O2,
    float qscale)
{
    constexpr int K = D_MODEL, N = D_MODEL;
    __shared__ char As_[128 * 64 * 2];   // 16 KB
    __shared__ char Bs_[128 * 64 * 2];   // 16 KB

    const int y = QKV ? (int)blockIdx.y : 0;
    const unsigned short* Ap = (y == 0) ? A0 : (y == 1) ? A1 : A2;
    const unsigned short* Wb = (y == 0) ? W0 : (y == 1) ? W1 : W2;
    const float* bias = (y == 0) ? B0 : (y == 1) ? B1 : B2;

    const int tid  = threadIdx.x;
    const int lane = tid & 63;
    const int wave = tid >> 6;
    const int wr = (wave >> 1) * 64;
    const int wc = (wave & 1) * 64;
    const int wg = ((int)blockIdx.x & 7) * 64 + ((int)blockIdx.x >> 3);
    const int n0 = (wg & 7) * 128;
    const int m0 = (wg >> 3) * 128;
    const int l15 = lane & 15, h16 = lane >> 4;

    f32x4 acc[4][4] = {};

    for (int kt = 0; kt < K; kt += 64) {
        __syncthreads();   // previous tile's reads done before overwrite
        #pragma unroll
        for (int i = 0; i < 4; ++i) {
            int chunk = tid + i * 256;
            int r = chunk >> 3, c16 = chunk & 7;
            int cs = (c16 ^ (r & 7)) * 8;        // pre-swizzled source column
            gload_lds16(Wb + (size_t)(n0 + r) * K + kt + cs, Bs_ + chunk * 16);
            gload_lds16(Ap + (size_t)(m0 + r) * K + kt + cs, As_ + chunk * 16);
        }
        __syncthreads();   // drains vmcnt (incl. gload_lds)

        #pragma unroll
        for (int kk = 0; kk < 2; ++kk) {
            bf16x8 af[4], bfr[4];
            #pragma unroll
            for (int mi = 0; mi < 4; ++mi) {
                int r = wr + mi * 16 + l15;
                af[mi] = *reinterpret_cast<const bf16x8*>(
                    As_ + ((r * 128 + kk * 64 + h16 * 16) ^ ((r & 7) << 4)));
            }
            #pragma unroll
            for (int ni = 0; ni < 4; ++ni) {
                int r = wc + ni * 16 + l15;
                bfr[ni] = *reinterpret_cast<const bf16x8*>(
                    Bs_ + ((r * 128 + kk * 64 + h16 * 16) ^ ((r & 7) << 4)));
            }
            #pragma unroll
            for (int mi = 0; mi < 4; ++mi)
                #pragma unroll
                for (int ni = 0; ni < 4; ++ni)
                    acc[mi][ni] = __builtin_amdgcn_mfma_f32_16x16x32_bf16(
                        af[mi], bfr[ni], acc[mi][ni], 0, 0, 0);
        }
    }

    const int rl = h16 * 4;
    #pragma unroll
    for (int mi = 0; mi < 4; ++mi) {
        #pragma unroll
        for (int ni = 0; ni < 4; ++ni) {
            int col = n0 + wc + ni * 16 + l15;
            float bv = bias[col];
            if constexpr (QKV) {
                float sc = (y == 0) ? qscale : 1.0f;
                if (y == 2) {
                    // V^T [B,H,DK,S], s-permuted (vperm_s)
                    int row0 = m0 + wr + mi * 16 + rl;
                    int bb = row0 >> 11, s0 = row0 & (SEQ - 1);
                    int sp = vperm_s(s0);
                    int h = col >> 6, dk = col & (DK - 1);
                    u16x4 o;
                    #pragma unroll
                    for (int r = 0; r < 4; ++r)
                        o[r] = f32_to_bf16_u(acc[mi][ni][r] + bv);
                    *reinterpret_cast<u16x4*>((unsigned short*)O2 +
                        (((size_t)bb * NH + h) * DK + dk) * SEQ + sp) = o;
                } else {
                    unsigned short* op = (unsigned short*)((y == 0) ? O0 : O1);
                    #pragma unroll
                    for (int r = 0; r < 4; ++r) {
                        int row = m0 + wr + mi * 16 + rl + r;
                        int bb = row >> 11, s = row & (SEQ - 1);
                        int h = col >> 6, dk = col & (DK - 1);
                        op[((((size_t)bb * NH + h) * SEQ) + s) * DK + dk]
                            = f32_to_bf16_u((acc[mi][ni][r] + bv) * sc);
                    }
                }
            } else {
                #pragma unroll
                for (int r = 0; r < 4; ++r) {
                    int row = m0 + wr + mi * 16 + rl + r;
                    ((float*)O0)[(size_t)row * N + col] = acc[mi][ni][r] + bv;
                }
            }
        }
    }
}

// ---------------------------------------------------------------------------
// fp32-A fallback GEMM (small-ws path), OMODE: 1=[B,H,S,DK], 2=V^T permuted.
// ---------------------------------------------------------------------------
template<int OMODE>
__global__ __launch_bounds__(256) void gemm_f32a(const float* __restrict__ Ap,
                                                 const unsigned short* __restrict__ Wb,
                                                 const float* __restrict__ bias,
                                                 void* __restrict__ outp,
                                                 float out_scale)
{
    constexpr int K = D_MODEL, N = D_MODEL;
    __shared__ char As_[128 * 64 * 2];
    __shared__ char Bs_[128 * 64 * 2];

    const int tid  = threadIdx.x;
    const int lane = tid & 63;
    const int wave = tid >> 6;
    const int wr = (wave >> 1) * 64;
    const int wc = (wave & 1) * 64;
    const int wg = ((int)blockIdx.x & 7) * 64 + ((int)blockIdx.x >> 3);
    const int n0 = (wg & 7) * 128;
    const int m0 = (wg >> 3) * 128;
    const int l15 = lane & 15, h16 = lane >> 4;

    f32x4 acc[4][4] = {};

    for (int kt = 0; kt < K; kt += 64) {
        __syncthreads();
        #pragma unroll
        for (int i = 0; i < 4; ++i) {
            int chunk = tid + i * 256;
            int r = chunk >> 3, c16 = chunk & 7;
            int cs = (c16 ^ (r & 7)) * 8;
            gload_lds16(Wb + (size_t)(n0 + r) * K + kt + cs, Bs_ + chunk * 16);
            const float* src = Ap + (size_t)(m0 + r) * K + kt + c16 * 8;
            fvec4 v0 = *reinterpret_cast<const fvec4*>(src);
            fvec4 v1 = *reinterpret_cast<const fvec4*>(src + 4);
            bf16x8 o;
            #pragma unroll
            for (int j = 0; j < 4; ++j) { o[j] = (__bf16)v0[j]; o[j + 4] = (__bf16)v1[j]; }
            *reinterpret_cast<bf16x8*>(As_ + ((chunk * 16) ^ ((r & 7) << 4))) = o;
        }
        __syncthreads();

        #pragma unroll
        for (int kk = 0; kk < 2; ++kk) {
            bf16x8 af[4], bfr[4];
            #pragma unroll
            for (int mi = 0; mi < 4; ++mi) {
                int r = wr + mi * 16 + l15;
                af[mi] = *reinterpret_cast<const bf16x8*>(
                    As_ + ((r * 128 + kk * 64 + h16 * 16) ^ ((r & 7) << 4)));
            }
            #pragma unroll
            for (int ni = 0; ni < 4; ++ni) {
                int r = wc + ni * 16 + l15;
                bfr[ni] = *reinterpret_cast<const bf16x8*>(
                    Bs_ + ((r * 128 + kk * 64 + h16 * 16) ^ ((r & 7) << 4)));
            }
            #pragma unroll
            for (int mi = 0; mi < 4; ++mi)
                #pragma unroll
                for (int ni = 0; ni < 4; ++ni)
                    acc[mi][ni] = __builtin_amdgcn_mfma_f32_16x16x32_bf16(
                        af[mi], bfr[ni], acc[mi][ni], 0, 0, 0);
        }
    }

    const int rl = h16 * 4;
    #pragma unroll
    for (int mi = 0; mi < 4; ++mi) {
        #pragma unroll
        for (int ni = 0; ni < 4; ++ni) {
            int col = n0 + wc + ni * 16 + l15;
            float bv = bias[col];
            if constexpr (OMODE == 2) {
                int row0 = m0 + wr + mi * 16 + rl;
                int bb = row0 >> 11, s0 = row0 & (SEQ - 1);
                int sp = vperm_s(s0);
                int h = col >> 6, dk = col & (DK - 1);
                u16x4 o;
                #pragma unroll
                for (int r = 0; r < 4; ++r)
                    o[r] = f32_to_bf16_u((acc[mi][ni][r] + bv) * out_scale);
                *reinterpret_cast<u16x4*>((unsigned short*)outp +
                    (((size_t)bb * NH + h) * DK + dk) * SEQ + sp) = o;
            } else {
                #pragma unroll
                for (int r = 0; r < 4; ++r) {
                    int row = m0 + wr + mi * 16 + rl + r;
                    int bb = row >> 11, s = row & (SEQ - 1);
                    int h = col >> 6, dk = col & (DK - 1);
                    ((unsigned short*)outp)[((((size_t)bb * NH + h) * SEQ) + s) * DK + dk]
                        = f32_to_bf16_u((acc[mi][ni][r] + bv) * out_scale);
                }
            }
        }
    }
}

// ---------------------------------------------------------------------------
// Flash attention, swapped-QK^T in-register softmax.
// Sync template: R7-PROVEN reg-load-early -> compute buf[cur] -> ds_write
// buf[cur^1] -> ONE barrier (R9's gload-dbuf variant raced across replays).
// V^T arrives s-PERMUTED (vperm_s), so the PV B-frag is LANE-LOCAL: lane
// (q,hi)'s own sT[kt][(ks&1)*8 + 0..7] are its 4 B-words in order -- zero
// shfl / cndmask in the pack (was 2 shfl + ~8 selects per 16-k block).
// max-reduce via v_max3 tree.  All ds_read_b128 wave-linear, 0 conflicts.
// Defer-max THR=11 (log2 domain); Q pre-scaled by 0.125*log2(e).
// ---------------------------------------------------------------------------
__global__ __launch_bounds__(512, 4) void attn_kernel(const unsigned short* __restrict__ qb,
                                                      const unsigned short* __restrict__ kb,
                                                      const unsigned short* __restrict__ vt,
                                                      unsigned short* __restrict__ ob)
{
    constexpr float THR = 11.0f;
    __shared__ char lds[32768];   // [2 bufs][K 8KB | V 8KB]

    const int tid  = threadIdx.x;
    const int lane = tid & 63;
    const int tl31 = lane & 31;
    const int hi   = lane >> 5;
    const int wave = tid >> 6;
    const int wg   = ((int)blockIdx.x & 7) * 64 + ((int)blockIdx.x >> 3);
    const int bh   = wg >> 3;
    const int q0   = (wg & 7) * 256;
    const size_t base  = (size_t)bh * SEQ * DK;   // K: [s][dk]
    const size_t baseT = (size_t)bh * DK * SEQ;   // V^T: [dk][s-permuted]

    const int k_kt = tid >> 8, k_kd = (tid >> 6) & 3, k_hi = (tid >> 5) & 1, k_tl = tid & 31;
    const size_t k_goff = base + (size_t)(k_kt * 32 + k_tl) * DK + k_kd * 16 + k_hi * 8;
    const int v_tg = tid >> 6, v_dh = (tid >> 5) & 1, v_dl = tid & 31;
    const size_t v_goff = baseT + (size_t)(v_dh * 32 + v_dl) * SEQ + v_tg * 8;

    // Q fragments: B-operand, col=lane&31=q, k = kd*16 + hi*8 + j
    bf16x8 qf[4];
    #pragma unroll
    for (int kd = 0; kd < 4; ++kd)
        qf[kd] = *reinterpret_cast<const bf16x8*>(
            qb + base + (size_t)(q0 + wave * 32 + tl31) * DK + kd * 16 + hi * 8);

    f32x16 oaccT[2] = {};      // [dh], col=q, row=crow(r,hi)=d
    float m_run = -1e30f, l_run = 0.f;

    // prologue: reg-load tile 0, write buf 0
    {
        u16x8 kreg = *reinterpret_cast<const u16x8*>(kb + k_goff);
        u16x8 vreg = *reinterpret_cast<const u16x8*>(vt + v_goff);
        *reinterpret_cast<u16x8*>(lds + tid * 16) = kreg;
        *reinterpret_cast<u16x8*>(lds + 8192 + tid * 16) = vreg;
    }
    __syncthreads();

    for (int t = 0; t < 32; ++t) {
        const int cur = t & 1;
        const char* Kr = lds + cur * 16384;
        const char* Vr = Kr + 8192;

        // issue next tile's global loads early (latency hides under compute)
        u16x8 kreg, vreg;
        if (t < 31) {
            const int t0n = (t + 1) * 64;
            kreg = *reinterpret_cast<const u16x8*>(kb + k_goff + (size_t)t0n * DK);
            vreg = *reinterpret_cast<const u16x8*>(vt + v_goff + t0n);
        }

        // ---- QK^T: 8 MFMA, 8 wave-linear b128 K reads ----
        f32x16 sT[2] = {};
        #pragma unroll
        for (int kt = 0; kt < 2; ++kt)
            #pragma unroll
            for (int kd = 0; kd < 4; ++kd) {
                bf16x8 kf = *reinterpret_cast<const bf16x8*>(Kr + kt * 4096 + kd * 1024 + lane * 16);
                sT[kt] = __builtin_amdgcn_mfma_f32_32x32x16_bf16(kf, qf[kd], sT[kt], 0, 0, 0);
            }

        // ---- softmax: v_max3 tree max, shfl_xor cross-half, defer-max ----
        float m;
        {
            float tm[2];
            #pragma unroll
            for (int kt = 0; kt < 2; ++kt) {
                float g0 = mx3(sT[kt][0],  sT[kt][1],  sT[kt][2]);
                float g1 = mx3(sT[kt][3],  sT[kt][4],  sT[kt][5]);
                float g2 = mx3(sT[kt][6],  sT[kt][7],  sT[kt][8]);
                float g3 = mx3(sT[kt][9],  sT[kt][10], sT[kt][11]);
                float g4 = mx3(sT[kt][12], sT[kt][13], sT[kt][14]);
                tm[kt] = fmaxf(mx3(g0, g1, g2), mx3(g3, g4, sT[kt][15]));
            }
            m = fmaxf(tm[0], tm[1]);
            m = fmaxf(m, __shfl_xor(m, 32));
        }
        if (__any(m > m_run + THR)) {
            float mn = fmaxf(m_run, m);
            float al = exp2_fast(m_run - mn);
            m_run = mn;
            l_run *= al;
            oaccT[0] *= al;
            oaccT[1] *= al;
        }
        {
            float rs0 = 0.f, rs1 = 0.f, rs2 = 0.f, rs3 = 0.f;
            #pragma unroll
            for (int kt = 0; kt < 2; ++kt)
                #pragma unroll
                for (int i = 0; i < 16; i += 4) {
                    float p0 = exp2_fast(sT[kt][i + 0] - m_run);
                    float p1 = exp2_fast(sT[kt][i + 1] - m_run);
                    float p2 = exp2_fast(sT[kt][i + 2] - m_run);
                    float p3 = exp2_fast(sT[kt][i + 3] - m_run);
                    sT[kt][i + 0] = p0; sT[kt][i + 1] = p1;
                    sT[kt][i + 2] = p2; sT[kt][i + 3] = p3;
                    rs0 += p0; rs1 += p1; rs2 += p2; rs3 += p3;
                }
            float rs = (rs0 + rs1) + (rs2 + rs3);
            rs += __shfl_xor(rs, 32);
            l_run += rs;
        }

        // ---- PV: O^T += V^T . P^T ; lane-local B-frag (permuted V^T) ----
        // B slots k = hi*8+j of 16-k block ks come straight from this lane's
        // sT[ks>>1][(ks&1)*8 + 0..7]; A slots hold V[pi^-1(k)] -- matched.
        #pragma unroll
        for (int ks = 0; ks < 4; ++ks) {
            bf16x8 vfA0 = *reinterpret_cast<const bf16x8*>(Vr + ks * 2048 + hi * 1024 + tl31 * 16);
            bf16x8 vfA1 = *reinterpret_cast<const bf16x8*>(Vr + ks * 2048 + hi * 1024 + 512 + tl31 * 16);
            const int kt = ks >> 1, r0 = (ks & 1) * 8;
            u32x4 w;
            w[0] = cvt_pk_bf16(sT[kt][r0 + 0], sT[kt][r0 + 1]);
            w[1] = cvt_pk_bf16(sT[kt][r0 + 2], sT[kt][r0 + 3]);
            w[2] = cvt_pk_bf16(sT[kt][r0 + 4], sT[kt][r0 + 5]);
            w[3] = cvt_pk_bf16(sT[kt][r0 + 6], sT[kt][r0 + 7]);
            bf16x8 pa = __builtin_bit_cast(bf16x8, w);
            oaccT[0] = __builtin_amdgcn_mfma_f32_32x32x16_bf16(vfA0, pa, oaccT[0], 0, 0, 0);
            oaccT[1] = __builtin_amdgcn_mfma_f32_32x32x16_bf16(vfA1, pa, oaccT[1], 0, 0, 0);
        }

        // ---- write next tile into the other buffer (R7-proven placement) ----
        if (t < 31) {
            char* Kw = lds + (cur ^ 1) * 16384;
            *reinterpret_cast<u16x8*>(Kw + tid * 16) = kreg;
            *reinterpret_cast<u16x8*>(Kw + 8192 + tid * 16) = vreg;
        }
        __syncthreads();
    }

    // ---- epilogue: per-wave LDS transpose (O^T -> O), coalesced stores ----
    char* myregion = lds + wave * 4096;   // 32 rows x 128 B, swizzled
    const int bb = bh >> 4, h = bh & 15;
    {
        float rl = 1.0f / l_run;
        #pragma unroll
        for (int dh = 0; dh < 2; ++dh)
            #pragma unroll
            for (int r = 0; r < 16; ++r) {
                int dl = (r & 3) + 8 * (r >> 2) + 4 * hi + 32 * dh;
                int boff = (tl31 * 128 + dl * 2) ^ ((tl31 & 7) << 4);
                *reinterpret_cast<unsigned short*>(myregion + boff) =
                    f32_to_bf16_u(oaccT[dh][r] * rl);
            }
        #pragma unroll
        for (int c = 0; c < 4; ++c) {
            int chunk = lane + c * 64;
            int row = chunk >> 3, c16 = chunk & 7;
            int boff = (row * 128 + c16 * 16) ^ ((row & 7) << 4);
            u16x8 v = *reinterpret_cast<const u16x8*>(myregion + boff);
            size_t tok = (size_t)(bb * SEQ) + q0 + wave * 32 + row;
            *reinterpret_cast<u16x8*>(ob + tok * D_MODEL + h * DK + c16 * 8) = v;
        }
    }
}

extern "C" void kernel_launch(void* const* d_in, const int* in_sizes, int n_in,
                              void* d_out, int out_size, void* d_ws, size_t ws_size,
                              hipStream_t stream)
{
    const float* Q  = (const float*)d_in[0];
    const float* K_ = (const float*)d_in[1];
    const float* V  = (const float*)d_in[2];
    const float* Wq = (const float*)d_in[3];
    const float* bq = (const float*)d_in[4];
    const float* Wk = (const float*)d_in[5];
    const float* bk = (const float*)d_in[6];
    const float* Wv = (const float*)d_in[7];
    const float* bv = (const float*)d_in[8];
    const float* Wo = (const float*)d_in[9];
    const float* bo = (const float*)d_in[10];
    float* out = (float*)d_out;

    const size_t SZ = (size_t)M_TOK * D_MODEL;   // 8M elements
    const size_t WZ = (size_t)D_MODEL * D_MODEL; // 1M elements
    unsigned short* qh_ = (unsigned short*)d_ws; // [B,H,S,DK] bf16
    unsigned short* kh_ = qh_ + SZ;
    unsigned short* vh_ = kh_ + SZ;              // V^T: [B,H,DK,S] bf16, s-permuted
    unsigned short* ah_ = vh_ + SZ;              // [B*S, D_MODEL] bf16
    unsigned short* wqb = ah_ + SZ;              // bf16 weights (contiguous x4)
    unsigned short* wkb = wqb + WZ;
    unsigned short* wvb = wkb + WZ;
    unsigned short* wob = wvb + WZ;
    unsigned short* qbf = wob + WZ;              // bf16 inputs (contiguous x3)
    unsigned short* kbf = qbf + SZ;
    unsigned short* vbf = kbf + SZ;

    const bool big = ws_size >= (size_t)(4 * SZ + 4 * WZ + 3 * SZ) * 2;
    const float qscale = 0.125f * 1.4426950408889634f;  // exp2-domain softmax

    cvt4<<<dim3((int)(WZ / 8 / 256), 4), 256, 0, stream>>>(Wq, Wk, Wv, Wo, wqb, (int)(WZ / 8));

    if (big) {
        cvt3<<<dim3((int)(SZ / 8 / 256), 3), 256, 0, stream>>>(Q, K_, V, qbf, (int)(SZ / 8));
        gemm_bf<true><<<dim3(512, 3), 256, 0, stream>>>(
            qbf, wqb, bq, qh_,  kbf, wkb, bk, kh_,  vbf, wvb, bv, vh_, qscale);
    } else {
        gemm_f32a<1><<<512, 256, 0, stream>>>(Q,  wqb, bq, qh_, qscale);
        gemm_f32a<1><<<512, 256, 0, stream>>>(K_, wkb, bk, kh_, 1.0f);
        gemm_f32a<2><<<512, 256, 0, stream>>>(V,  wvb, bv, vh_, 1.0f);
    }
    attn_kernel<<<512, 512, 0, stream>>>(qh_, kh_, vh_, ah_);
    gemm_bf<false><<<dim3(512, 1), 256, 0, stream>>>(
        ah_, wob, bo, out,  nullptr, nullptr, nullptr, nullptr,
        nullptr, nullptr, nullptr, nullptr, 1.0f);
}

// Round 12
// 203.570 us; speedup vs baseline: 2.3668x; 1.0006x over previous
//
#include <hip/hip_runtime.h>
#include <hip/hip_bf16.h>

typedef float  f32x4  __attribute__((ext_vector_type(4)));
typedef float  f32x16 __attribute__((ext_vector_type(16)));
typedef float  fvec4  __attribute__((ext_vector_type(4)));
typedef __bf16 bf16x8 __attribute__((ext_vector_type(8)));
typedef unsigned short u16x4 __attribute__((ext_vector_type(4)));
typedef unsigned short u16x8 __attribute__((ext_vector_type(8)));
typedef unsigned int   u32x4 __attribute__((ext_vector_type(4)));

#define DEVINL __device__ __forceinline__

constexpr int D_MODEL = 1024;
constexpr int NH      = 16;
constexpr int DK      = 64;
constexpr int SEQ     = 2048;
constexpr int BATCH   = 4;
constexpr int M_TOK   = BATCH * SEQ;   // 8192

DEVINL unsigned short f32_to_bf16_u(float f) {
    unsigned int u = __builtin_bit_cast(unsigned int, f);
    u = (u + 0x7FFFu + ((u >> 16) & 1u)) >> 16;
    return (unsigned short)u;
}

DEVINL float exp2_fast(float x) { return __builtin_amdgcn_exp2f(x); }
DEVINL float mx3(float a, float b, float c) { return fmaxf(fmaxf(a, b), c); }

DEVINL unsigned cvt_pk_bf16(float lo, float hi_) {
    unsigned d;
    asm("v_cvt_pk_bf16_f32 %0, %1, %2" : "=v"(d) : "v"(lo), "v"(hi_));
    return d;
}

DEVINL void gload_lds16(const void* g, void* l) {
    __builtin_amdgcn_global_load_lds(
        (const __attribute__((address_space(1))) void*)g,
        (__attribute__((address_space(3))) void*)l, 16, 0, 0);
}

// s-axis permutation for V^T storage: involution swapping s&15 in {4..7} with
// {8..11}. Makes the PV B-frag lane-local (zero cross-lane exchange).
// 4-runs (s0%4==0) stay contiguous -> u16x4 store keeps working.
DEVINL int vperm_s(int s0) { return (s0 & ~12) | ((s0 & 4) << 1) | ((s0 & 8) >> 1); }

// ---------------------------------------------------------------------------
// fused fp32 -> bf16 convert: 4 weight matrices (one dispatch, ~4 us).
// ---------------------------------------------------------------------------
__global__ __launch_bounds__(256) void cvt4(const float* __restrict__ a,
                                            const float* __restrict__ b,
                                            const float* __restrict__ c,
                                            const float* __restrict__ d,
                                            unsigned short* __restrict__ dst, int n8)
{
    int y = blockIdx.y;
    const float* s = (y == 0) ? a : (y == 1) ? b : (y == 2) ? c : d;
    size_t i = blockIdx.x * 256 + threadIdx.x;
    fvec4 v0 = *reinterpret_cast<const fvec4*>(s + i * 8);
    fvec4 v1 = *reinterpret_cast<const fvec4*>(s + i * 8 + 4);
    bf16x8 o;
    #pragma unroll
    for (int j = 0; j < 4; ++j) { o[j] = (__bf16)v0[j]; o[j + 4] = (__bf16)v1[j]; }
    *reinterpret_cast<bf16x8*>(dst + ((size_t)y * n8 + i) * 8) = o;
}

// ---------------------------------------------------------------------------
// QKV projection GEMM, fp32 A staged in registers (conversion fused into
// staging -- no separate cvt pass over the 8192x1024 inputs), bf16 W via
// global_load_lds with pre-swizzled source.  m97-proven 2-barrier structure
// (R7-passing launch pattern).  OMODE: 1=[B,H,S,DK]; 2=V^T [B,H,DK,S],
// s-permuted by vperm_s.
// ---------------------------------------------------------------------------
template<int OMODE>
__global__ __launch_bounds__(256) void gemm_f32a(const float* __restrict__ Ap,
                                                 const unsigned short* __restrict__ Wb,
                                                 const float* __restrict__ bias,
                                                 void* __restrict__ outp,
                                                 float out_scale)
{
    constexpr int K = D_MODEL;
    __shared__ char As_[128 * 64 * 2];
    __shared__ char Bs_[128 * 64 * 2];

    const int tid  = threadIdx.x;
    const int lane = tid & 63;
    const int wave = tid >> 6;
    const int wr = (wave >> 1) * 64;
    const int wc = (wave & 1) * 64;
    const int wg = ((int)blockIdx.x & 7) * 64 + ((int)blockIdx.x >> 3);
    const int n0 = (wg & 7) * 128;
    const int m0 = (wg >> 3) * 128;
    const int l15 = lane & 15, h16 = lane >> 4;

    f32x4 acc[4][4] = {};

    for (int kt = 0; kt < K; kt += 64) {
        __syncthreads();
        #pragma unroll
        for (int i = 0; i < 4; ++i) {
            int chunk = tid + i * 256;
            int r = chunk >> 3, c16 = chunk & 7;
            int cs = (c16 ^ (r & 7)) * 8;        // pre-swizzled source column
            gload_lds16(Wb + (size_t)(n0 + r) * K + kt + cs, Bs_ + chunk * 16);
            const float* src = Ap + (size_t)(m0 + r) * K + kt + c16 * 8;
            fvec4 v0 = *reinterpret_cast<const fvec4*>(src);
            fvec4 v1 = *reinterpret_cast<const fvec4*>(src + 4);
            bf16x8 o;
            #pragma unroll
            for (int j = 0; j < 4; ++j) { o[j] = (__bf16)v0[j]; o[j + 4] = (__bf16)v1[j]; }
            *reinterpret_cast<bf16x8*>(As_ + ((chunk * 16) ^ ((r & 7) << 4))) = o;
        }
        __syncthreads();

        #pragma unroll
        for (int kk = 0; kk < 2; ++kk) {
            bf16x8 af[4], bfr[4];
            #pragma unroll
            for (int mi = 0; mi < 4; ++mi) {
                int r = wr + mi * 16 + l15;
                af[mi] = *reinterpret_cast<const bf16x8*>(
                    As_ + ((r * 128 + kk * 64 + h16 * 16) ^ ((r & 7) << 4)));
            }
            #pragma unroll
            for (int ni = 0; ni < 4; ++ni) {
                int r = wc + ni * 16 + l15;
                bfr[ni] = *reinterpret_cast<const bf16x8*>(
                    Bs_ + ((r * 128 + kk * 64 + h16 * 16) ^ ((r & 7) << 4)));
            }
            #pragma unroll
            for (int mi = 0; mi < 4; ++mi)
                #pragma unroll
                for (int ni = 0; ni < 4; ++ni)
                    acc[mi][ni] = __builtin_amdgcn_mfma_f32_16x16x32_bf16(
                        af[mi], bfr[ni], acc[mi][ni], 0, 0, 0);
        }
    }

    const int rl = h16 * 4;
    #pragma unroll
    for (int mi = 0; mi < 4; ++mi) {
        #pragma unroll
        for (int ni = 0; ni < 4; ++ni) {
            int col = n0 + wc + ni * 16 + l15;
            float bv = bias[col];
            if constexpr (OMODE == 2) {
                int row0 = m0 + wr + mi * 16 + rl;
                int bb = row0 >> 11, s0 = row0 & (SEQ - 1);
                int sp = vperm_s(s0);
                int h = col >> 6, dk = col & (DK - 1);
                u16x4 o;
                #pragma unroll
                for (int r = 0; r < 4; ++r)
                    o[r] = f32_to_bf16_u((acc[mi][ni][r] + bv) * out_scale);
                *reinterpret_cast<u16x4*>((unsigned short*)outp +
                    (((size_t)bb * NH + h) * DK + dk) * SEQ + sp) = o;
            } else {
                #pragma unroll
                for (int r = 0; r < 4; ++r) {
                    int row = m0 + wr + mi * 16 + rl + r;
                    int bb = row >> 11, s = row & (SEQ - 1);
                    int h = col >> 6, dk = col & (DK - 1);
                    ((unsigned short*)outp)[((((size_t)bb * NH + h) * SEQ) + s) * DK + dk]
                        = f32_to_bf16_u((acc[mi][ni][r] + bv) * out_scale);
                }
            }
        }
    }
}

// ---------------------------------------------------------------------------
// O-projection GEMM, bf16 A via global_load_lds both sides (pre-swizzled
// sources), fp32 [M,N] output.  m97-proven 2-barrier structure.
// ---------------------------------------------------------------------------
__global__ __launch_bounds__(256) void gemm_obf(const unsigned short* __restrict__ Ap,
                                                const unsigned short* __restrict__ Wb,
                                                const float* __restrict__ bias,
                                                float* __restrict__ outp)
{
    constexpr int K = D_MODEL, N = D_MODEL;
    __shared__ char As_[128 * 64 * 2];
    __shared__ char Bs_[128 * 64 * 2];

    const int tid  = threadIdx.x;
    const int lane = tid & 63;
    const int wave = tid >> 6;
    const int wr = (wave >> 1) * 64;
    const int wc = (wave & 1) * 64;
    const int wg = ((int)blockIdx.x & 7) * 64 + ((int)blockIdx.x >> 3);
    const int n0 = (wg & 7) * 128;
    const int m0 = (wg >> 3) * 128;
    const int l15 = lane & 15, h16 = lane >> 4;

    f32x4 acc[4][4] = {};

    for (int kt = 0; kt < K; kt += 64) {
        __syncthreads();
        #pragma unroll
        for (int i = 0; i < 4; ++i) {
            int chunk = tid + i * 256;
            int r = chunk >> 3, c16 = chunk & 7;
            int cs = (c16 ^ (r & 7)) * 8;
            gload_lds16(Wb + (size_t)(n0 + r) * K + kt + cs, Bs_ + chunk * 16);
            gload_lds16(Ap + (size_t)(m0 + r) * K + kt + cs, As_ + chunk * 16);
        }
        __syncthreads();

        #pragma unroll
        for (int kk = 0; kk < 2; ++kk) {
            bf16x8 af[4], bfr[4];
            #pragma unroll
            for (int mi = 0; mi < 4; ++mi) {
                int r = wr + mi * 16 + l15;
                af[mi] = *reinterpret_cast<const bf16x8*>(
                    As_ + ((r * 128 + kk * 64 + h16 * 16) ^ ((r & 7) << 4)));
            }
            #pragma unroll
            for (int ni = 0; ni < 4; ++ni) {
                int r = wc + ni * 16 + l15;
                bfr[ni] = *reinterpret_cast<const bf16x8*>(
                    Bs_ + ((r * 128 + kk * 64 + h16 * 16) ^ ((r & 7) << 4)));
            }
            #pragma unroll
            for (int mi = 0; mi < 4; ++mi)
                #pragma unroll
                for (int ni = 0; ni < 4; ++ni)
                    acc[mi][ni] = __builtin_amdgcn_mfma_f32_16x16x32_bf16(
                        af[mi], bfr[ni], acc[mi][ni], 0, 0, 0);
        }
    }

    const int rl = h16 * 4;
    #pragma unroll
    for (int mi = 0; mi < 4; ++mi) {
        #pragma unroll
        for (int ni = 0; ni < 4; ++ni) {
            int col = n0 + wc + ni * 16 + l15;
            float bv = bias[col];
            #pragma unroll
            for (int r = 0; r < 4; ++r) {
                int row = m0 + wr + mi * 16 + rl + r;
                outp[(size_t)row * N + col] = acc[mi][ni][r] + bv;
            }
        }
    }
}

// ---------------------------------------------------------------------------
// Flash attention, swapped-QK^T in-register softmax (R7-proven sync template:
// reg-load-early -> compute buf[cur] -> ds_write buf[cur^1] -> ONE barrier).
// V^T arrives s-PERMUTED (vperm_s) -> PV B-frag is LANE-LOCAL (zero shfl).
// T5: s_setprio(1) around both MFMA clusters (independent blocks/CU desync
// -> the m191 regime where setprio pays).
// max3-tree max; defer-max THR=11 (log2); Q pre-scaled by 0.125*log2(e).
// ---------------------------------------------------------------------------
__global__ __launch_bounds__(512, 4) void attn_kernel(const unsigned short* __restrict__ qb,
                                                      const unsigned short* __restrict__ kb,
                                                      const unsigned short* __restrict__ vt,
                                                      unsigned short* __restrict__ ob)
{
    constexpr float THR = 11.0f;
    __shared__ char lds[32768];   // [2 bufs][K 8KB | V 8KB]

    const int tid  = threadIdx.x;
    const int lane = tid & 63;
    const int tl31 = lane & 31;
    const int hi   = lane >> 5;
    const int wave = tid >> 6;
    const int wg   = ((int)blockIdx.x & 7) * 64 + ((int)blockIdx.x >> 3);
    const int bh   = wg >> 3;
    const int q0   = (wg & 7) * 256;
    const size_t base  = (size_t)bh * SEQ * DK;   // K: [s][dk]
    const size_t baseT = (size_t)bh * DK * SEQ;   // V^T: [dk][s-permuted]

    const int k_kt = tid >> 8, k_kd = (tid >> 6) & 3, k_hi = (tid >> 5) & 1, k_tl = tid & 31;
    const size_t k_goff = base + (size_t)(k_kt * 32 + k_tl) * DK + k_kd * 16 + k_hi * 8;
    const int v_tg = tid >> 6, v_dh = (tid >> 5) & 1, v_dl = tid & 31;
    const size_t v_goff = baseT + (size_t)(v_dh * 32 + v_dl) * SEQ + v_tg * 8;

    // Q fragments: B-operand, col=lane&31=q, k = kd*16 + hi*8 + j
    bf16x8 qf[4];
    #pragma unroll
    for (int kd = 0; kd < 4; ++kd)
        qf[kd] = *reinterpret_cast<const bf16x8*>(
            qb + base + (size_t)(q0 + wave * 32 + tl31) * DK + kd * 16 + hi * 8);

    f32x16 oaccT[2] = {};      // [dh], col=q, row=crow(r,hi)=d
    float m_run = -1e30f, l_run = 0.f;

    // prologue: reg-load tile 0, write buf 0
    {
        u16x8 kreg = *reinterpret_cast<const u16x8*>(kb + k_goff);
        u16x8 vreg = *reinterpret_cast<const u16x8*>(vt + v_goff);
        *reinterpret_cast<u16x8*>(lds + tid * 16) = kreg;
        *reinterpret_cast<u16x8*>(lds + 8192 + tid * 16) = vreg;
    }
    __syncthreads();

    for (int t = 0; t < 32; ++t) {
        const int cur = t & 1;
        const char* Kr = lds + cur * 16384;
        const char* Vr = Kr + 8192;

        // issue next tile's global loads early (latency hides under compute)
        u16x8 kreg, vreg;
        if (t < 31) {
            const int t0n = (t + 1) * 64;
            kreg = *reinterpret_cast<const u16x8*>(kb + k_goff + (size_t)t0n * DK);
            vreg = *reinterpret_cast<const u16x8*>(vt + v_goff + t0n);
        }

        // ---- QK^T: 8 MFMA, 8 wave-linear b128 K reads ----
        f32x16 sT[2] = {};
        __builtin_amdgcn_s_setprio(1);
        #pragma unroll
        for (int kt = 0; kt < 2; ++kt)
            #pragma unroll
            for (int kd = 0; kd < 4; ++kd) {
                bf16x8 kf = *reinterpret_cast<const bf16x8*>(Kr + kt * 4096 + kd * 1024 + lane * 16);
                sT[kt] = __builtin_amdgcn_mfma_f32_32x32x16_bf16(kf, qf[kd], sT[kt], 0, 0, 0);
            }
        __builtin_amdgcn_s_setprio(0);

        // ---- softmax: v_max3 tree max, shfl_xor cross-half, defer-max ----
        float m;
        {
            float tm[2];
            #pragma unroll
            for (int kt = 0; kt < 2; ++kt) {
                float g0 = mx3(sT[kt][0],  sT[kt][1],  sT[kt][2]);
                float g1 = mx3(sT[kt][3],  sT[kt][4],  sT[kt][5]);
                float g2 = mx3(sT[kt][6],  sT[kt][7],  sT[kt][8]);
                float g3 = mx3(sT[kt][9],  sT[kt][10], sT[kt][11]);
                float g4 = mx3(sT[kt][12], sT[kt][13], sT[kt][14]);
                tm[kt] = fmaxf(mx3(g0, g1, g2), mx3(g3, g4, sT[kt][15]));
            }
            m = fmaxf(tm[0], tm[1]);
            m = fmaxf(m, __shfl_xor(m, 32));
        }
        if (__any(m > m_run + THR)) {
            float mn = fmaxf(m_run, m);
            float al = exp2_fast(m_run - mn);
            m_run = mn;
            l_run *= al;
            oaccT[0] *= al;
            oaccT[1] *= al;
        }
        {
            float rs0 = 0.f, rs1 = 0.f, rs2 = 0.f, rs3 = 0.f;
            #pragma unroll
            for (int kt = 0; kt < 2; ++kt)
                #pragma unroll
                for (int i = 0; i < 16; i += 4) {
                    float p0 = exp2_fast(sT[kt][i + 0] - m_run);
                    float p1 = exp2_fast(sT[kt][i + 1] - m_run);
                    float p2 = exp2_fast(sT[kt][i + 2] - m_run);
                    float p3 = exp2_fast(sT[kt][i + 3] - m_run);
                    sT[kt][i + 0] = p0; sT[kt][i + 1] = p1;
                    sT[kt][i + 2] = p2; sT[kt][i + 3] = p3;
                    rs0 += p0; rs1 += p1; rs2 += p2; rs3 += p3;
                }
            float rs = (rs0 + rs1) + (rs2 + rs3);
            rs += __shfl_xor(rs, 32);
            l_run += rs;
        }

        // ---- PV: O^T += V^T . P^T ; lane-local B-frag (permuted V^T) ----
        __builtin_amdgcn_s_setprio(1);
        #pragma unroll
        for (int ks = 0; ks < 4; ++ks) {
            bf16x8 vfA0 = *reinterpret_cast<const bf16x8*>(Vr + ks * 2048 + hi * 1024 + tl31 * 16);
            bf16x8 vfA1 = *reinterpret_cast<const bf16x8*>(Vr + ks * 2048 + hi * 1024 + 512 + tl31 * 16);
            const int kt = ks >> 1, r0 = (ks & 1) * 8;
            u32x4 w;
            w[0] = cvt_pk_bf16(sT[kt][r0 + 0], sT[kt][r0 + 1]);
            w[1] = cvt_pk_bf16(sT[kt][r0 + 2], sT[kt][r0 + 3]);
            w[2] = cvt_pk_bf16(sT[kt][r0 + 4], sT[kt][r0 + 5]);
            w[3] = cvt_pk_bf16(sT[kt][r0 + 6], sT[kt][r0 + 7]);
            bf16x8 pa = __builtin_bit_cast(bf16x8, w);
            oaccT[0] = __builtin_amdgcn_mfma_f32_32x32x16_bf16(vfA0, pa, oaccT[0], 0, 0, 0);
            oaccT[1] = __builtin_amdgcn_mfma_f32_32x32x16_bf16(vfA1, pa, oaccT[1], 0, 0, 0);
        }
        __builtin_amdgcn_s_setprio(0);

        // ---- write next tile into the other buffer (R7-proven placement) ----
        if (t < 31) {
            char* Kw = lds + (cur ^ 1) * 16384;
            *reinterpret_cast<u16x8*>(Kw + tid * 16) = kreg;
            *reinterpret_cast<u16x8*>(Kw + 8192 + tid * 16) = vreg;
        }
        __syncthreads();
    }

    // ---- epilogue: per-wave LDS transpose (O^T -> O), coalesced stores ----
    char* myregion = lds + wave * 4096;   // 32 rows x 128 B, swizzled
    const int bb = bh >> 4, h = bh & 15;
    {
        float rl = 1.0f / l_run;
        #pragma unroll
        for (int dh = 0; dh < 2; ++dh)
            #pragma unroll
            for (int r = 0; r < 16; ++r) {
                int dl = (r & 3) + 8 * (r >> 2) + 4 * hi + 32 * dh;
                int boff = (tl31 * 128 + dl * 2) ^ ((tl31 & 7) << 4);
                *reinterpret_cast<unsigned short*>(myregion + boff) =
                    f32_to_bf16_u(oaccT[dh][r] * rl);
            }
        #pragma unroll
        for (int c = 0; c < 4; ++c) {
            int chunk = lane + c * 64;
            int row = chunk >> 3, c16 = chunk & 7;
            int boff = (row * 128 + c16 * 16) ^ ((row & 7) << 4);
            u16x8 v = *reinterpret_cast<const u16x8*>(myregion + boff);
            size_t tok = (size_t)(bb * SEQ) + q0 + wave * 32 + row;
            *reinterpret_cast<u16x8*>(ob + tok * D_MODEL + h * DK + c16 * 8) = v;
        }
    }
}

extern "C" void kernel_launch(void* const* d_in, const int* in_sizes, int n_in,
                              void* d_out, int out_size, void* d_ws, size_t ws_size,
                              hipStream_t stream)
{
    const float* Q  = (const float*)d_in[0];
    const float* K_ = (const float*)d_in[1];
    const float* V  = (const float*)d_in[2];
    const float* Wq = (const float*)d_in[3];
    const float* bq = (const float*)d_in[4];
    const float* Wk = (const float*)d_in[5];
    const float* bk = (const float*)d_in[6];
    const float* Wv = (const float*)d_in[7];
    const float* bv = (const float*)d_in[8];
    const float* Wo = (const float*)d_in[9];
    const float* bo = (const float*)d_in[10];
    float* out = (float*)d_out;

    const size_t SZ = (size_t)M_TOK * D_MODEL;   // 8M elements
    const size_t WZ = (size_t)D_MODEL * D_MODEL; // 1M elements
    unsigned short* qh_ = (unsigned short*)d_ws; // [B,H,S,DK] bf16
    unsigned short* kh_ = qh_ + SZ;
    unsigned short* vh_ = kh_ + SZ;              // V^T: [B,H,DK,S] bf16, s-permuted
    unsigned short* ah_ = vh_ + SZ;              // [B*S, D_MODEL] bf16
    unsigned short* wqb = ah_ + SZ;              // bf16 weights (contiguous x4)
    unsigned short* wkb = wqb + WZ;
    unsigned short* wvb = wkb + WZ;
    unsigned short* wob = wvb + WZ;

    const float qscale = 0.125f * 1.4426950408889634f;  // exp2-domain softmax

    cvt4<<<dim3((int)(WZ / 8 / 256), 4), 256, 0, stream>>>(Wq, Wk, Wv, Wo, wqb, (int)(WZ / 8));

    gemm_f32a<1><<<512, 256, 0, stream>>>(Q,  wqb, bq, qh_, qscale);
    gemm_f32a<1><<<512, 256, 0, stream>>>(K_, wkb, bk, kh_, 1.0f);
    gemm_f32a<2><<<512, 256, 0, stream>>>(V,  wvb, bv, vh_, 1.0f);
    attn_kernel<<<512, 512, 0, stream>>>(qh_, kh_, vh_, ah_);
    gemm_obf<<<512, 256, 0, stream>>>(ah_, wob, bo, out);
}